// Round 6
// baseline (468.655 us; speedup 1.0000x reference)
//
#include <hip/hip_runtime.h>

typedef float  f32x4 __attribute__((ext_vector_type(4)));
typedef short  s16x8 __attribute__((ext_vector_type(8)));
typedef unsigned int u32x4 __attribute__((ext_vector_type(4)));

#define DEVINL __device__ __forceinline__

DEVINL float4 ld4(const float* p) { return *reinterpret_cast<const float4*>(p); }

// split 8 fp32 into bf16 hi + bf16 lo fragments — pure integer ops (R5-proven).
DEVINL void split8(const float4& f0, const float4& f1, s16x8& hi, s16x8& lo) {
  unsigned hb[8], lb[8];
  const float f[8] = {f0.x, f0.y, f0.z, f0.w, f1.x, f1.y, f1.z, f1.w};
  #pragma unroll
  for (int j = 0; j < 8; ++j) {
    unsigned u = __float_as_uint(f[j]);
    unsigned h = u & 0xffff0000u;
    float l = f[j] - __uint_as_float(h);
    hb[j] = h;
    lb[j] = __float_as_uint(l) & 0xffff0000u;
  }
  u32x4 H = {(hb[0] >> 16) | hb[1], (hb[2] >> 16) | hb[3],
             (hb[4] >> 16) | hb[5], (hb[6] >> 16) | hb[7]};
  u32x4 L = {(lb[0] >> 16) | lb[1], (lb[2] >> 16) | lb[3],
             (lb[4] >> 16) | lb[5], (lb[6] >> 16) | lb[7]};
  hi = __builtin_bit_cast(s16x8, H);
  lo = __builtin_bit_cast(s16x8, L);
}

// ---------------------------------------------------------------------------
// Fused W conversion: all 4 weight matrices -> transposed bf16 hi/lo
// ---------------------------------------------------------------------------
DEVINL void conv_w_body(const float* W, unsigned short* hiT, unsigned short* loT,
                        int K, int idx) {
  int k = idx >> 7, c = idx & 127;
  float f = W[idx];
  unsigned u = __float_as_uint(f);
  unsigned hb = (u + 0x7fffu + ((u >> 16) & 1u)) >> 16;       // RNE bf16
  float hf = __uint_as_float(hb << 16);
  float d = f - hf;
  unsigned v = __float_as_uint(d);
  unsigned lb = (v + 0x7fffu + ((v >> 16) & 1u)) >> 16;
  hiT[(size_t)c * K + k] = (unsigned short)hb;
  loT[(size_t)c * K + k] = (unsigned short)lb;
}

__global__ __launch_bounds__(256) void conv_w4_kernel(
    const float* __restrict__ W1, const float* __restrict__ W2,
    const float* __restrict__ W3, const float* __restrict__ W4,
    unsigned short* __restrict__ w1h, unsigned short* __restrict__ w1l,
    unsigned short* __restrict__ w2h, unsigned short* __restrict__ w2l,
    unsigned short* __restrict__ w3h, unsigned short* __restrict__ w3l,
    unsigned short* __restrict__ w4h, unsigned short* __restrict__ w4l)
{
  int b = blockIdx.x;
  // segments: 64 blocks (K=128), 96 (K=192), 96 (K=192), 128 (K=256)
  if (b < 64)       conv_w_body(W1, w1h, w1l, 128, b * 256 + threadIdx.x);
  else if (b < 160) conv_w_body(W2, w2h, w2l, 192, (b - 64) * 256 + threadIdx.x);
  else if (b < 256) conv_w_body(W3, w3h, w3l, 192, (b - 160) * 256 + threadIdx.x);
  else              conv_w_body(W4, w4h, w4l, 256, (b - 256) * 256 + threadIdx.x);
}

// ---------------------------------------------------------------------------
// CSR build (R2-proven)
// ---------------------------------------------------------------------------
__global__ __launch_bounds__(256) void hist_kernel(
    const int* __restrict__ dst, int* __restrict__ deg, int E)
{
  int e = blockIdx.x * 256 + threadIdx.x;
  if (e < E) atomicAdd(&deg[dst[e]], 1);
}

__global__ __launch_bounds__(256) void scan_blk_kernel(
    const int* __restrict__ in, int* __restrict__ excl, int* __restrict__ bsum, int n)
{
  __shared__ int tmp[256];
  int t = threadIdx.x;
  int i = blockIdx.x * 256 + t;
  int v = (i < n) ? in[i] : 0;
  tmp[t] = v;
  __syncthreads();
  #pragma unroll
  for (int off = 1; off < 256; off <<= 1) {
    int add = (t >= off) ? tmp[t - off] : 0;
    __syncthreads();
    tmp[t] += add;
    __syncthreads();
  }
  if (i < n) excl[i] = tmp[t] - v;
  if (t == 255 && bsum) bsum[blockIdx.x] = tmp[255];
}

__global__ __launch_bounds__(256) void finalize_rp_kernel(
    const int* __restrict__ excl, const int* __restrict__ boff,
    int* __restrict__ rp, int* __restrict__ cursor, int N, int E)
{
  int i = blockIdx.x * 256 + threadIdx.x;
  if (i < N) { int v = excl[i] + boff[i >> 8]; rp[i] = v; cursor[i] = v; }
  if (i == N) rp[N] = E;
}

__global__ __launch_bounds__(256) void scatter_kernel(
    const int* __restrict__ dst, int* __restrict__ cursor, int* __restrict__ eidx, int E)
{
  int e = blockIdx.x * 256 + threadIdx.x;
  if (e >= E) return;
  int d = dst[e];
  int pos = atomicAdd(&cursor[d], 1);
  eidx[pos] = e;
}

// ---------------------------------------------------------------------------
// Fused layer-1 aggregation: one wave per node, both targets in one pass.
//   aggE[n][c]  = sum_e ef[e][c]
//   aggH1[n][c] = sum_e nf[src[e]][c]
// ---------------------------------------------------------------------------
__global__ __launch_bounds__(256) void csr_agg_l1_kernel(
    const float* __restrict__ ef, const float* __restrict__ nf,
    const int* __restrict__ src, const int* __restrict__ eidx,
    const int* __restrict__ rp, float* __restrict__ aggE,
    float* __restrict__ aggH1, int N)
{
  int node = (int)((blockIdx.x * 256u + threadIdx.x) >> 6);
  int lane = threadIdx.x & 63;
  if (node >= N) return;
  int beg = rp[node], end = rp[node + 1];
  float ea = 0.f, eb = 0.f, ha = 0.f, hb = 0.f;
  int k = beg;
  for (; k + 1 < end; k += 2) {
    int a = eidx[k], b = eidx[k + 1];
    int sa = src[a], sb = src[b];
    ea += ef[(size_t)a * 64 + lane];
    eb += ef[(size_t)b * 64 + lane];
    ha += nf[(size_t)sa * 64 + lane];
    hb += nf[(size_t)sb * 64 + lane];
  }
  if (k < end) {
    int a = eidx[k];
    ea += ef[(size_t)a * 64 + lane];
    ha += nf[(size_t)src[a] * 64 + lane];
  }
  aggE [(size_t)node * 64 + lane] = ea + eb;
  aggH1[(size_t)node * 64 + lane] = ha + hb;
}

// ---------------------------------------------------------------------------
// CSR aggregation D=128 (layer 2), one wave per node (R2-proven MODE 2)
// ---------------------------------------------------------------------------
__global__ __launch_bounds__(256) void csr_agg128_kernel(
    const float* __restrict__ X, const int* __restrict__ src,
    const int* __restrict__ eidx, const int* __restrict__ rp,
    float* __restrict__ out, int N)
{
  int node = (int)((blockIdx.x * 256u + threadIdx.x) >> 6);
  int lane = threadIdx.x & 63;
  if (node >= N) return;
  int beg = rp[node], end = rp[node + 1];

  const float2* X2 = (const float2*)X;
  float2 a0 = make_float2(0.f, 0.f), a1 = a0, a2 = a0, a3 = a0;
  int k = beg;
  for (; k + 3 < end; k += 4) {
    int e0 = eidx[k], e1 = eidx[k+1], e2 = eidx[k+2], e3 = eidx[k+3];
    int r0 = src[e0], r1 = src[e1], r2 = src[e2], r3 = src[e3];
    float2 v0 = X2[(size_t)r0 * 64 + lane];
    float2 v1 = X2[(size_t)r1 * 64 + lane];
    float2 v2 = X2[(size_t)r2 * 64 + lane];
    float2 v3 = X2[(size_t)r3 * 64 + lane];
    a0.x += v0.x; a0.y += v0.y; a1.x += v1.x; a1.y += v1.y;
    a2.x += v2.x; a2.y += v2.y; a3.x += v3.x; a3.y += v3.y;
  }
  for (; k < end; ++k) {
    int r = src[eidx[k]];
    float2 v = X2[(size_t)r * 64 + lane];
    a0.x += v.x; a0.y += v.y;
  }
  ((float2*)out)[(size_t)node * 64 + lane] =
      make_float2((a0.x + a1.x) + (a2.x + a3.x), (a0.y + a1.y) + (a2.y + a3.y));
}

// ---------------------------------------------------------------------------
// MFMA split-bf16 GEMM: out[N][128] = post([X1||X2] @ W + B)
// Block = 128 rows; wave w owns rows [w*32, w*32+32), ALL 128 cols.
// A rows loaded+split exactly once per block. acc[2][8].
// ---------------------------------------------------------------------------
template<int C1, int C2, int POST>
__global__ __launch_bounds__(256, 2) void gemm_mfma_kernel(
    const float* __restrict__ X1, const float* __restrict__ X2,
    const unsigned short* __restrict__ WtHi, const unsigned short* __restrict__ WtLo,
    const float* __restrict__ Bv, const int* __restrict__ deg,
    float* __restrict__ out, int n)
{
  constexpr int K = C1 + C2;
  const int lane = threadIdx.x & 63;
  const int w = threadIdx.x >> 6;
  const int base = blockIdx.x * 128;
  const int l15 = lane & 15;
  const int lg = lane >> 4;

  f32x4 acc[2][8] = {};

  #pragma unroll
  for (int k0 = 0; k0 < K; k0 += 32) {
    const float* srcp = (k0 < C1) ? X1 : X2;
    const int C  = (k0 < C1) ? C1 : C2;
    const int ca = ((k0 < C1) ? k0 : (k0 - C1)) + lg * 8;

    s16x8 ah[2], al[2];
    #pragma unroll
    for (int mi = 0; mi < 2; ++mi) {
      int row = base + w * 32 + mi * 16 + l15;
      if (row >= n) row = n - 1;
      float4 f0 = ld4(srcp + (size_t)row * C + ca);
      float4 f1 = ld4(srcp + (size_t)row * C + ca + 4);
      split8(f0, f1, ah[mi], al[mi]);
    }

    s16x8 bh[8], bl[8];
    const int kb = k0 + lg * 8;
    #pragma unroll
    for (int ni = 0; ni < 8; ++ni) {
      size_t off = (size_t)(ni * 16 + l15) * K + kb;
      bh[ni] = *reinterpret_cast<const s16x8*>(WtHi + off);
      bl[ni] = *reinterpret_cast<const s16x8*>(WtLo + off);
    }

    #pragma unroll
    for (int mi = 0; mi < 2; ++mi)
      #pragma unroll
      for (int ni = 0; ni < 8; ++ni) {
        acc[mi][ni] = __builtin_amdgcn_mfma_f32_16x16x32_bf16(ah[mi], bh[ni], acc[mi][ni], 0, 0, 0);
        acc[mi][ni] = __builtin_amdgcn_mfma_f32_16x16x32_bf16(ah[mi], bl[ni], acc[mi][ni], 0, 0, 0);
        acc[mi][ni] = __builtin_amdgcn_mfma_f32_16x16x32_bf16(al[mi], bh[ni], acc[mi][ni], 0, 0, 0);
      }
  }

  float bv[8];
  #pragma unroll
  for (int ni = 0; ni < 8; ++ni) bv[ni] = Bv[ni * 16 + l15];

  #pragma unroll
  for (int mi = 0; mi < 2; ++mi) {
    #pragma unroll
    for (int r = 0; r < 4; ++r) {
      int grow = base + w * 32 + mi * 16 + lg * 4 + r;
      if (grow >= n) continue;
      float inv = 1.0f, msk = 1.0f;
      if (POST == 0) {
        float dg = (float)deg[grow];
        inv = 1.0f / fmaxf(dg, 1.0f);
        msk = dg > 0.0f ? 1.0f : 0.0f;
      }
      float* op = out + (size_t)grow * 128 + l15;
      #pragma unroll
      for (int ni = 0; ni < 8; ++ni) {
        float v = acc[mi][ni][r];
        v = (POST == 0) ? (v * inv + bv[ni] * msk) : fmaxf(v + bv[ni], 0.0f);
        op[ni * 16] = v;
      }
    }
  }
}

// ---------------------------------------------------------------------------
// Predictor
// ---------------------------------------------------------------------------
__global__ __launch_bounds__(256) void pred_node_kernel(
    const float* __restrict__ h2, const float* __restrict__ Wp,
    float* __restrict__ pt, int n)
{
  __shared__ float xs[128 * 65];
  __shared__ float wl[2560];
  const int tid = threadIdx.x;
  const int base = blockIdx.x * 64;

  for (int i = tid; i < 2560; i += 256) wl[i] = Wp[i];
  #pragma unroll
  for (int it = 0; it < 8; ++it) {
    int f = tid + it * 256;
    int r = f >> 5;
    int c = (f & 31) << 2;
    int i = base + r; if (i >= n) i = n - 1;
    float4 v = ld4(h2 + (size_t)i * 128 + c);
    xs[(c + 0) * 65 + r] = v.x; xs[(c + 1) * 65 + r] = v.y;
    xs[(c + 2) * 65 + r] = v.z; xs[(c + 3) * 65 + r] = v.w;
  }
  __syncthreads();

  int rr = tid & 63;
  int g = tid >> 6;
  int wbase[5];
  #pragma unroll
  for (int jj = 0; jj < 5; ++jj) {
    int j = g * 5 + jj;
    wbase[jj] = (j < 10) ? j : (1280 + j - 10);
  }
  float acc[5] = {};
  for (int k = 0; k < 128; ++k) {
    float xv = xs[k * 65 + rr];
    #pragma unroll
    for (int jj = 0; jj < 5; ++jj)
      acc[jj] = fmaf(xv, wl[wbase[jj] + k * 10], acc[jj]);
  }
  int ig = base + rr;
  if (ig < n) {
    #pragma unroll
    for (int jj = 0; jj < 5; ++jj)
      pt[(size_t)ig * 20 + g * 5 + jj] = acc[jj];
  }
}

// float2 per thread: idx = e*5 + jj covers out[e][2jj:2jj+2]
__global__ __launch_bounds__(256) void pred_edge_kernel(
    const float* __restrict__ pt, const int* __restrict__ src, const int* __restrict__ dst,
    const float* __restrict__ bp, float* __restrict__ out, int E)
{
  int idx = blockIdx.x * 256 + threadIdx.x;
  if (idx >= E * 5) return;
  int e = idx / 5;
  int jj = idx - e * 5;
  int s = src[e], d = dst[e];
  const float2* p2 = (const float2*)pt;
  float2 a = p2[(size_t)s * 10 + jj];
  float2 b = p2[(size_t)d * 10 + 5 + jj];
  float2 c = ((const float2*)bp)[jj];
  ((float2*)out)[idx] = make_float2(a.x + b.x + c.x, a.y + b.y + c.y);
}

extern "C" void kernel_launch(void* const* d_in, const int* in_sizes, int n_in,
                              void* d_out, int out_size, void* d_ws, size_t ws_size,
                              hipStream_t stream) {
  const float* nfeats = (const float*)d_in[0];
  const float* efeats = (const float*)d_in[1];
  const int*   src    = (const int*)d_in[2];
  const int*   dst    = (const int*)d_in[3];
  const float* Wm1 = (const float*)d_in[4];
  const float* bm1 = (const float*)d_in[5];
  const float* Wa1 = (const float*)d_in[6];
  const float* ba1 = (const float*)d_in[7];
  const float* Wm2 = (const float*)d_in[8];
  const float* bm2 = (const float*)d_in[9];
  const float* Wa2 = (const float*)d_in[10];
  const float* ba2 = (const float*)d_in[11];
  const float* Wp  = (const float*)d_in[12];
  const float* bp  = (const float*)d_in[13];

  const int N = in_sizes[0] / 64;
  const int E = in_sizes[2];
  const int nblk = (N + 255) / 256;

  // ---- int region (R5-proven layout) ----
  int* ip     = (int*)d_ws;
  int* deg_i  = ip;                                  // N
  int* rp     = ip + (size_t)N;                      // N+1 (padded to +4)
  int* eidx   = ip + 2 * (size_t)N + 4;              // E
  int* scr    = ip + 2 * (size_t)N + 4 + E;          // 2N+512 scratch
  int* excl   = scr;                                 // N
  int* cursor = scr + (size_t)N;                     // N
  int* bsum   = scr + 2 * (size_t)N;                 // 256
  int* boff   = bsum + 256;                          // 256

  // bf16 weight overlay onto scr (393,216 B <= 402,048 B)
  unsigned short* w1h = (unsigned short*)scr;        // 128*128
  unsigned short* w1l = w1h + 128 * 128;
  unsigned short* w2h = w1l + 128 * 128;             // 192*128
  unsigned short* w2l = w2h + 192 * 128;
  unsigned short* w3h = w2l + 192 * 128;             // 192*128
  unsigned short* w3l = w3h + 192 * 128;
  unsigned short* w4h = w3l + 192 * 128;             // 256*128
  unsigned short* w4l = w4h + 256 * 128;

  // ---- float region (R5-proven layout) ----
  size_t fbase = (4 * (size_t)N + 516 + (size_t)E + 3) & ~(size_t)3;
  float* fp    = (float*)d_ws;
  float* aggE  = fp + fbase;                    // N*64
  float* aggH1 = aggE  + (size_t)N * 64;        // N*64  (reused as pt)
  float* aggH2 = aggH1 + (size_t)N * 64;        // N*128 (reused as h2)
  float* hn    = aggH2 + (size_t)N * 128;       // N*128
  float* h1    = hn    + (size_t)N * 128;       // N*128
  float* h2    = aggH2;
  float* pt    = aggH1;
  float* out   = (float*)d_out;

  hipMemsetAsync(deg_i, 0, (size_t)N * sizeof(int), stream);

  int gridE  = (E + 255) / 256;
  int gridN  = (N + 127) / 128;
  int gridNW = ((N * 64) + 255) / 256;

  // CSR build
  hist_kernel<<<gridE, 256, 0, stream>>>(dst, deg_i, E);
  scan_blk_kernel<<<nblk, 256, 0, stream>>>(deg_i, excl, bsum, N);
  scan_blk_kernel<<<1, 256, 0, stream>>>(bsum, boff, nullptr, nblk);
  finalize_rp_kernel<<<(N + 256) / 256, 256, 0, stream>>>(excl, boff, rp, cursor, N, E);
  scatter_kernel<<<gridE, 256, 0, stream>>>(dst, cursor, eidx, E);

  // W conversions AFTER scatter (overlay onto dead CSR scratch)
  conv_w4_kernel<<<384, 256, 0, stream>>>(Wm1, Wa1, Wm2, Wa2,
                                          w1h, w1l, w2h, w2l, w3h, w3l, w4h, w4l);

  // layer 1
  csr_agg_l1_kernel<<<gridNW, 256, 0, stream>>>(efeats, nfeats, src, eidx, rp, aggE, aggH1, N);
  gemm_mfma_kernel<64, 64, 0><<<gridN, 256, 0, stream>>>(aggH1, aggE, w1h, w1l, bm1, deg_i, hn, N);
  gemm_mfma_kernel<64, 128, 1><<<gridN, 256, 0, stream>>>(nfeats, hn, w2h, w2l, ba1, nullptr, h1, N);

  // layer 2
  csr_agg128_kernel<<<gridNW, 256, 0, stream>>>(h1, src, eidx, rp, aggH2, N);
  gemm_mfma_kernel<128, 64, 0><<<gridN, 256, 0, stream>>>(aggH2, aggE, w3h, w3l, bm2, deg_i, hn, N);
  gemm_mfma_kernel<128, 128, 1><<<gridN, 256, 0, stream>>>(h1, hn, w4h, w4l, ba2, nullptr, h2, N);

  // predictor
  pred_node_kernel<<<(N + 63) / 64, 256, 0, stream>>>(h2, Wp, pt, N);
  pred_edge_kernel<<<(E * 5 + 255) / 256, 256, 0, stream>>>(pt, src, dst, bp, out, E);
}

// Round 7
// 410.383 us; speedup vs baseline: 1.1420x; 1.1420x over previous
//
#include <hip/hip_runtime.h>

typedef float  f32x4 __attribute__((ext_vector_type(4)));
typedef short  s16x8 __attribute__((ext_vector_type(8)));
typedef unsigned int u32x4 __attribute__((ext_vector_type(4)));

#define DEVINL __device__ __forceinline__

DEVINL float4 ld4(const float* p) { return *reinterpret_cast<const float4*>(p); }

// split 8 fp32 into bf16 hi + bf16 lo fragments — pure integer ops (R5-proven).
DEVINL void split8(const float4& f0, const float4& f1, s16x8& hi, s16x8& lo) {
  unsigned hb[8], lb[8];
  const float f[8] = {f0.x, f0.y, f0.z, f0.w, f1.x, f1.y, f1.z, f1.w};
  #pragma unroll
  for (int j = 0; j < 8; ++j) {
    unsigned u = __float_as_uint(f[j]);
    unsigned h = u & 0xffff0000u;
    float l = f[j] - __uint_as_float(h);
    hb[j] = h;
    lb[j] = __float_as_uint(l) & 0xffff0000u;
  }
  u32x4 H = {(hb[0] >> 16) | hb[1], (hb[2] >> 16) | hb[3],
             (hb[4] >> 16) | hb[5], (hb[6] >> 16) | hb[7]};
  u32x4 L = {(lb[0] >> 16) | lb[1], (lb[2] >> 16) | lb[3],
             (lb[4] >> 16) | lb[5], (lb[6] >> 16) | lb[7]};
  hi = __builtin_bit_cast(s16x8, H);
  lo = __builtin_bit_cast(s16x8, L);
}

// ---------------------------------------------------------------------------
// Fused W conversion: all 4 weight matrices -> transposed bf16 hi/lo
// ---------------------------------------------------------------------------
DEVINL void conv_w_body(const float* W, unsigned short* hiT, unsigned short* loT,
                        int K, int idx) {
  int k = idx >> 7, c = idx & 127;
  float f = W[idx];
  unsigned u = __float_as_uint(f);
  unsigned hb = (u + 0x7fffu + ((u >> 16) & 1u)) >> 16;       // RNE bf16
  float hf = __uint_as_float(hb << 16);
  float d = f - hf;
  unsigned v = __float_as_uint(d);
  unsigned lb = (v + 0x7fffu + ((v >> 16) & 1u)) >> 16;
  hiT[(size_t)c * K + k] = (unsigned short)hb;
  loT[(size_t)c * K + k] = (unsigned short)lb;
}

__global__ __launch_bounds__(256) void conv_w4_kernel(
    const float* __restrict__ W1, const float* __restrict__ W2,
    const float* __restrict__ W3, const float* __restrict__ W4,
    unsigned short* __restrict__ w1h, unsigned short* __restrict__ w1l,
    unsigned short* __restrict__ w2h, unsigned short* __restrict__ w2l,
    unsigned short* __restrict__ w3h, unsigned short* __restrict__ w3l,
    unsigned short* __restrict__ w4h, unsigned short* __restrict__ w4l)
{
  int b = blockIdx.x;
  if (b < 64)       conv_w_body(W1, w1h, w1l, 128, b * 256 + threadIdx.x);
  else if (b < 160) conv_w_body(W2, w2h, w2l, 192, (b - 64) * 256 + threadIdx.x);
  else if (b < 256) conv_w_body(W3, w3h, w3l, 192, (b - 160) * 256 + threadIdx.x);
  else              conv_w_body(W4, w4h, w4l, 256, (b - 256) * 256 + threadIdx.x);
}

// ---------------------------------------------------------------------------
// CSR build
// ---------------------------------------------------------------------------
__global__ __launch_bounds__(256) void hist_kernel(
    const int* __restrict__ dst, int* __restrict__ deg, int E)
{
  int e = blockIdx.x * 256 + threadIdx.x;
  if (e < E) atomicAdd(&deg[dst[e]], 1);
}

__global__ __launch_bounds__(256) void scan_blk_kernel(
    const int* __restrict__ in, int* __restrict__ excl, int* __restrict__ bsum, int n)
{
  __shared__ int tmp[256];
  int t = threadIdx.x;
  int i = blockIdx.x * 256 + t;
  int v = (i < n) ? in[i] : 0;
  tmp[t] = v;
  __syncthreads();
  #pragma unroll
  for (int off = 1; off < 256; off <<= 1) {
    int add = (t >= off) ? tmp[t - off] : 0;
    __syncthreads();
    tmp[t] += add;
    __syncthreads();
  }
  if (i < n) excl[i] = tmp[t] - v;
  if (t == 255 && bsum) bsum[blockIdx.x] = tmp[255];
}

__global__ __launch_bounds__(256) void finalize_rp_kernel(
    const int* __restrict__ excl, const int* __restrict__ boff,
    int* __restrict__ rp, int* __restrict__ cursor, int N, int E)
{
  int i = blockIdx.x * 256 + threadIdx.x;
  if (i < N) { int v = excl[i] + boff[i >> 8]; rp[i] = v; cursor[i] = v; }
  if (i == N) rp[N] = E;
}

// scatter also emits srcp[pos] = src[e]  (dst-sorted source array)
__global__ __launch_bounds__(256) void scatter_kernel(
    const int* __restrict__ dst, const int* __restrict__ src,
    int* __restrict__ cursor, int* __restrict__ eidx, int* __restrict__ srcp, int E)
{
  int e = blockIdx.x * 256 + threadIdx.x;
  if (e >= E) return;
  int d = dst[e];
  int pos = atomicAdd(&cursor[d], 1);
  eidx[pos] = e;
  srcp[pos] = src[e];
}

// ---------------------------------------------------------------------------
// Fused layer-1 aggregation: one wave per node, 8-deep MLP, scalar indices.
//   aggE[n][c]  = sum_e ef[e][c]      (nontemporal: ef read exactly once)
//   aggH1[n][c] = sum_e nf[srcp][c]
// ---------------------------------------------------------------------------
__global__ __launch_bounds__(256) void csr_agg_l1_kernel(
    const float* __restrict__ ef, const float* __restrict__ nf,
    const int* __restrict__ eidx, const int* __restrict__ srcp,
    const int* __restrict__ rp, float* __restrict__ aggE,
    float* __restrict__ aggH1, int N)
{
  int node = (int)((blockIdx.x * 256u + threadIdx.x) >> 6);
  node = __builtin_amdgcn_readfirstlane(node);     // wave-uniform -> s_load indices
  int lane = threadIdx.x & 63;
  if (node >= N) return;
  int beg = rp[node], end = rp[node + 1];

  float ea[4] = {0.f, 0.f, 0.f, 0.f}, ha[4] = {0.f, 0.f, 0.f, 0.f};
  int k = beg;
  for (; k + 7 < end; k += 8) {
    int e[8], s[8];
    #pragma unroll
    for (int j = 0; j < 8; ++j) { e[j] = eidx[k + j]; s[j] = srcp[k + j]; }
    float ev[8], hv[8];
    #pragma unroll
    for (int j = 0; j < 8; ++j) {
      ev[j] = __builtin_nontemporal_load(ef + (size_t)e[j] * 64 + lane);
      hv[j] = nf[(size_t)s[j] * 64 + lane];
    }
    #pragma unroll
    for (int j = 0; j < 8; ++j) { ea[j & 3] += ev[j]; ha[j & 3] += hv[j]; }
  }
  for (; k < end; ++k) {
    ea[0] += __builtin_nontemporal_load(ef + (size_t)eidx[k] * 64 + lane);
    ha[0] += nf[(size_t)srcp[k] * 64 + lane];
  }
  aggE [(size_t)node * 64 + lane] = (ea[0] + ea[1]) + (ea[2] + ea[3]);
  aggH1[(size_t)node * 64 + lane] = (ha[0] + ha[1]) + (ha[2] + ha[3]);
}

// ---------------------------------------------------------------------------
// Layer-2 aggregation D=128: one wave per node, srcp only, 8-deep MLP.
// ---------------------------------------------------------------------------
__global__ __launch_bounds__(256) void csr_agg128_kernel(
    const float* __restrict__ X, const int* __restrict__ srcp,
    const int* __restrict__ rp, float* __restrict__ out, int N)
{
  int node = (int)((blockIdx.x * 256u + threadIdx.x) >> 6);
  node = __builtin_amdgcn_readfirstlane(node);
  int lane = threadIdx.x & 63;
  if (node >= N) return;
  int beg = rp[node], end = rp[node + 1];

  const float2* X2 = (const float2*)X;
  float2 a[4];
  #pragma unroll
  for (int j = 0; j < 4; ++j) a[j] = make_float2(0.f, 0.f);
  int k = beg;
  for (; k + 7 < end; k += 8) {
    int s[8];
    #pragma unroll
    for (int j = 0; j < 8; ++j) s[j] = srcp[k + j];
    float2 v[8];
    #pragma unroll
    for (int j = 0; j < 8; ++j) v[j] = X2[(size_t)s[j] * 64 + lane];
    #pragma unroll
    for (int j = 0; j < 8; ++j) { a[j & 3].x += v[j].x; a[j & 3].y += v[j].y; }
  }
  for (; k < end; ++k) {
    float2 v = X2[(size_t)srcp[k] * 64 + lane];
    a[0].x += v.x; a[0].y += v.y;
  }
  ((float2*)out)[(size_t)node * 64 + lane] =
      make_float2((a[0].x + a[1].x) + (a[2].x + a[3].x),
                  (a[0].y + a[1].y) + (a[2].y + a[3].y));
}

// ---------------------------------------------------------------------------
// MFMA split-bf16 GEMM (R6 structure): block = 128 rows, wave = 32 rows x 128 cols
// ---------------------------------------------------------------------------
template<int C1, int C2, int POST>
__global__ __launch_bounds__(256, 2) void gemm_mfma_kernel(
    const float* __restrict__ X1, const float* __restrict__ X2,
    const unsigned short* __restrict__ WtHi, const unsigned short* __restrict__ WtLo,
    const float* __restrict__ Bv, const int* __restrict__ deg,
    float* __restrict__ out, int n)
{
  constexpr int K = C1 + C2;
  const int lane = threadIdx.x & 63;
  const int w = threadIdx.x >> 6;
  const int base = blockIdx.x * 128;
  const int l15 = lane & 15;
  const int lg = lane >> 4;

  f32x4 acc[2][8] = {};

  #pragma unroll
  for (int k0 = 0; k0 < K; k0 += 32) {
    const float* srcp = (k0 < C1) ? X1 : X2;
    const int C  = (k0 < C1) ? C1 : C2;
    const int ca = ((k0 < C1) ? k0 : (k0 - C1)) + lg * 8;

    s16x8 ah[2], al[2];
    #pragma unroll
    for (int mi = 0; mi < 2; ++mi) {
      int row = base + w * 32 + mi * 16 + l15;
      if (row >= n) row = n - 1;
      float4 f0 = ld4(srcp + (size_t)row * C + ca);
      float4 f1 = ld4(srcp + (size_t)row * C + ca + 4);
      split8(f0, f1, ah[mi], al[mi]);
    }

    s16x8 bh[8], bl[8];
    const int kb = k0 + lg * 8;
    #pragma unroll
    for (int ni = 0; ni < 8; ++ni) {
      size_t off = (size_t)(ni * 16 + l15) * K + kb;
      bh[ni] = *reinterpret_cast<const s16x8*>(WtHi + off);
      bl[ni] = *reinterpret_cast<const s16x8*>(WtLo + off);
    }

    #pragma unroll
    for (int mi = 0; mi < 2; ++mi)
      #pragma unroll
      for (int ni = 0; ni < 8; ++ni) {
        acc[mi][ni] = __builtin_amdgcn_mfma_f32_16x16x32_bf16(ah[mi], bh[ni], acc[mi][ni], 0, 0, 0);
        acc[mi][ni] = __builtin_amdgcn_mfma_f32_16x16x32_bf16(ah[mi], bl[ni], acc[mi][ni], 0, 0, 0);
        acc[mi][ni] = __builtin_amdgcn_mfma_f32_16x16x32_bf16(al[mi], bh[ni], acc[mi][ni], 0, 0, 0);
      }
  }

  float bv[8];
  #pragma unroll
  for (int ni = 0; ni < 8; ++ni) bv[ni] = Bv[ni * 16 + l15];

  #pragma unroll
  for (int mi = 0; mi < 2; ++mi) {
    #pragma unroll
    for (int r = 0; r < 4; ++r) {
      int grow = base + w * 32 + mi * 16 + lg * 4 + r;
      if (grow >= n) continue;
      float inv = 1.0f, msk = 1.0f;
      if (POST == 0) {
        float dg = (float)deg[grow];
        inv = 1.0f / fmaxf(dg, 1.0f);
        msk = dg > 0.0f ? 1.0f : 0.0f;
      }
      float* op = out + (size_t)grow * 128 + l15;
      #pragma unroll
      for (int ni = 0; ni < 8; ++ni) {
        float v = acc[mi][ni][r];
        v = (POST == 0) ? (v * inv + bv[ni] * msk) : fmaxf(v + bv[ni], 0.0f);
        op[ni * 16] = v;
      }
    }
  }
}

// ---------------------------------------------------------------------------
// Predictor
// ---------------------------------------------------------------------------
__global__ __launch_bounds__(256) void pred_node_kernel(
    const float* __restrict__ h2, const float* __restrict__ Wp,
    float* __restrict__ pt, int n)
{
  __shared__ float xs[128 * 65];
  __shared__ float wl[2560];
  const int tid = threadIdx.x;
  const int base = blockIdx.x * 64;

  for (int i = tid; i < 2560; i += 256) wl[i] = Wp[i];
  #pragma unroll
  for (int it = 0; it < 8; ++it) {
    int f = tid + it * 256;
    int r = f >> 5;
    int c = (f & 31) << 2;
    int i = base + r; if (i >= n) i = n - 1;
    float4 v = ld4(h2 + (size_t)i * 128 + c);
    xs[(c + 0) * 65 + r] = v.x; xs[(c + 1) * 65 + r] = v.y;
    xs[(c + 2) * 65 + r] = v.z; xs[(c + 3) * 65 + r] = v.w;
  }
  __syncthreads();

  int rr = tid & 63;
  int g = tid >> 6;
  int wbase[5];
  #pragma unroll
  for (int jj = 0; jj < 5; ++jj) {
    int j = g * 5 + jj;
    wbase[jj] = (j < 10) ? j : (1280 + j - 10);
  }
  float acc[5] = {};
  for (int k = 0; k < 128; ++k) {
    float xv = xs[k * 65 + rr];
    #pragma unroll
    for (int jj = 0; jj < 5; ++jj)
      acc[jj] = fmaf(xv, wl[wbase[jj] + k * 10], acc[jj]);
  }
  int ig = base + rr;
  if (ig < n) {
    #pragma unroll
    for (int jj = 0; jj < 5; ++jj)
      pt[(size_t)ig * 20 + g * 5 + jj] = acc[jj];
  }
}

__global__ __launch_bounds__(256) void pred_edge_kernel(
    const float* __restrict__ pt, const int* __restrict__ src, const int* __restrict__ dst,
    const float* __restrict__ bp, float* __restrict__ out, int E)
{
  int idx = blockIdx.x * 256 + threadIdx.x;
  if (idx >= E * 5) return;
  int e = idx / 5;
  int jj = idx - e * 5;
  int s = src[e], d = dst[e];
  const float2* p2 = (const float2*)pt;
  float2 a = p2[(size_t)s * 10 + jj];
  float2 b = p2[(size_t)d * 10 + 5 + jj];
  float2 c = ((const float2*)bp)[jj];
  ((float2*)out)[idx] = make_float2(a.x + b.x + c.x, a.y + b.y + c.y);
}

extern "C" void kernel_launch(void* const* d_in, const int* in_sizes, int n_in,
                              void* d_out, int out_size, void* d_ws, size_t ws_size,
                              hipStream_t stream) {
  const float* nfeats = (const float*)d_in[0];
  const float* efeats = (const float*)d_in[1];
  const int*   src    = (const int*)d_in[2];
  const int*   dst    = (const int*)d_in[3];
  const float* Wm1 = (const float*)d_in[4];
  const float* bm1 = (const float*)d_in[5];
  const float* Wa1 = (const float*)d_in[6];
  const float* ba1 = (const float*)d_in[7];
  const float* Wm2 = (const float*)d_in[8];
  const float* bm2 = (const float*)d_in[9];
  const float* Wa2 = (const float*)d_in[10];
  const float* ba2 = (const float*)d_in[11];
  const float* Wp  = (const float*)d_in[12];
  const float* bp  = (const float*)d_in[13];

  const int N = in_sizes[0] / 64;
  const int E = in_sizes[2];
  const int nblk = (N + 255) / 256;

  // ---- int region (R5/R6-proven layout) ----
  int* ip     = (int*)d_ws;
  int* deg_i  = ip;                                  // N
  int* rp     = ip + (size_t)N;                      // N+1 (padded to +4)
  int* eidx   = ip + 2 * (size_t)N + 4;              // E
  int* scr    = ip + 2 * (size_t)N + 4 + E;          // 2N+512 scratch
  int* excl   = scr;                                 // N
  int* cursor = scr + (size_t)N;                     // N
  int* bsum   = scr + 2 * (size_t)N;                 // 256
  int* boff   = bsum + 256;                          // 256

  // bf16 weight overlay onto scr (393,216 B <= 402,048 B)
  unsigned short* w1h = (unsigned short*)scr;        // 128*128
  unsigned short* w1l = w1h + 128 * 128;
  unsigned short* w2h = w1l + 128 * 128;             // 192*128
  unsigned short* w2l = w2h + 192 * 128;
  unsigned short* w3h = w2l + 192 * 128;             // 192*128
  unsigned short* w3l = w3h + 192 * 128;
  unsigned short* w4h = w3l + 192 * 128;             // 256*128
  unsigned short* w4l = w4h + 256 * 128;

  // ---- float region (R5/R6-proven layout) ----
  size_t fbase = (4 * (size_t)N + 516 + (size_t)E + 3) & ~(size_t)3;
  float* fp    = (float*)d_ws;
  float* aggE  = fp + fbase;                    // N*64
  float* aggH1 = aggE  + (size_t)N * 64;        // N*64  (reused as pt)
  float* aggH2 = aggH1 + (size_t)N * 64;        // N*128 (reused as h2)
  float* hn    = aggH2 + (size_t)N * 128;       // N*128
  float* h1    = hn    + (size_t)N * 128;       // N*128
  float* h2    = aggH2;
  float* pt    = aggH1;
  float* out   = (float*)d_out;

  // srcp: NEW region appended after floats (+E ints; harness fills show ws ~800MB)
  int* srcp = (int*)(fp + fbase + (size_t)N * 512);

  hipMemsetAsync(deg_i, 0, (size_t)N * sizeof(int), stream);

  int gridE  = (E + 255) / 256;
  int gridN  = (N + 127) / 128;
  int gridNW = ((N * 64) + 255) / 256;

  // CSR build
  hist_kernel<<<gridE, 256, 0, stream>>>(dst, deg_i, E);
  scan_blk_kernel<<<nblk, 256, 0, stream>>>(deg_i, excl, bsum, N);
  scan_blk_kernel<<<1, 256, 0, stream>>>(bsum, boff, nullptr, nblk);
  finalize_rp_kernel<<<(N + 256) / 256, 256, 0, stream>>>(excl, boff, rp, cursor, N, E);
  scatter_kernel<<<gridE, 256, 0, stream>>>(dst, src, cursor, eidx, srcp, E);

  // W conversions AFTER scatter (overlay onto dead CSR scratch)
  conv_w4_kernel<<<384, 256, 0, stream>>>(Wm1, Wa1, Wm2, Wa2,
                                          w1h, w1l, w2h, w2l, w3h, w3l, w4h, w4l);

  // layer 1
  csr_agg_l1_kernel<<<gridNW, 256, 0, stream>>>(efeats, nfeats, eidx, srcp, rp, aggE, aggH1, N);
  gemm_mfma_kernel<64, 64, 0><<<gridN, 256, 0, stream>>>(aggH1, aggE, w1h, w1l, bm1, deg_i, hn, N);
  gemm_mfma_kernel<64, 128, 1><<<gridN, 256, 0, stream>>>(nfeats, hn, w2h, w2l, ba1, nullptr, h1, N);

  // layer 2
  csr_agg128_kernel<<<gridNW, 256, 0, stream>>>(h1, srcp, rp, aggH2, N);
  gemm_mfma_kernel<128, 64, 0><<<gridN, 256, 0, stream>>>(aggH2, aggE, w3h, w3l, bm2, deg_i, hn, N);
  gemm_mfma_kernel<128, 128, 1><<<gridN, 256, 0, stream>>>(h1, hn, w4h, w4l, ba2, nullptr, h2, N);

  // predictor
  pred_node_kernel<<<(N + 63) / 64, 256, 0, stream>>>(h2, Wp, pt, N);
  pred_edge_kernel<<<(E * 5 + 255) / 256, 256, 0, stream>>>(pt, src, dst, bp, out, E);
}

// Round 8
// 366.724 us; speedup vs baseline: 1.2780x; 1.1191x over previous
//
#include <hip/hip_runtime.h>

typedef float  f32x4 __attribute__((ext_vector_type(4)));
typedef short  s16x8 __attribute__((ext_vector_type(8)));
typedef unsigned int u32x4 __attribute__((ext_vector_type(4)));

#define DEVINL __device__ __forceinline__

DEVINL float4 ld4(const float* p) { return *reinterpret_cast<const float4*>(p); }

// split 8 fp32 into bf16 hi + bf16 lo fragments — pure integer ops (R5-proven).
DEVINL void split8(const float4& f0, const float4& f1, s16x8& hi, s16x8& lo) {
  unsigned hb[8], lb[8];
  const float f[8] = {f0.x, f0.y, f0.z, f0.w, f1.x, f1.y, f1.z, f1.w};
  #pragma unroll
  for (int j = 0; j < 8; ++j) {
    unsigned u = __float_as_uint(f[j]);
    unsigned h = u & 0xffff0000u;
    float l = f[j] - __uint_as_float(h);
    hb[j] = h;
    lb[j] = __float_as_uint(l) & 0xffff0000u;
  }
  u32x4 H = {(hb[0] >> 16) | hb[1], (hb[2] >> 16) | hb[3],
             (hb[4] >> 16) | hb[5], (hb[6] >> 16) | hb[7]};
  u32x4 L = {(lb[0] >> 16) | lb[1], (lb[2] >> 16) | lb[3],
             (lb[4] >> 16) | lb[5], (lb[6] >> 16) | lb[7]};
  hi = __builtin_bit_cast(s16x8, H);
  lo = __builtin_bit_cast(s16x8, L);
}

// ---------------------------------------------------------------------------
// Weight prep (fp32, exact-ish): Wc1 = Wm1 @ Wa1[64:192]   (128x128)
//                                Wc2 = Wm2 @ Wa2[128:256]  (192x128)
//                                bmw1 = bm1 @ Wa1[64:192], bmw2 = bm2 @ Wa2[128:256]
// One block per output row, 128 threads = output cols.
// ---------------------------------------------------------------------------
__global__ __launch_bounds__(128) void wprep_kernel(
    const float* __restrict__ Wm1, const float* __restrict__ Wa1, const float* __restrict__ bm1,
    const float* __restrict__ Wm2, const float* __restrict__ Wa2, const float* __restrict__ bm2,
    float* __restrict__ Wc1, float* __restrict__ Wc2,
    float* __restrict__ bmw1, float* __restrict__ bmw2)
{
  int b = blockIdx.x, j = threadIdx.x;
  float acc = 0.f;
  if (b < 128) {
    for (int k = 0; k < 128; ++k) acc = fmaf(Wm1[b * 128 + k], Wa1[(64 + k) * 128 + j], acc);
    Wc1[b * 128 + j] = acc;
  } else if (b < 320) {
    int i = b - 128;
    for (int k = 0; k < 128; ++k) acc = fmaf(Wm2[i * 128 + k], Wa2[(128 + k) * 128 + j], acc);
    Wc2[i * 128 + j] = acc;
  } else if (b == 320) {
    for (int k = 0; k < 128; ++k) acc = fmaf(bm1[k], Wa1[(64 + k) * 128 + j], acc);
    bmw1[j] = acc;
  } else {
    for (int k = 0; k < 128; ++k) acc = fmaf(bm2[k], Wa2[(128 + k) * 128 + j], acc);
    bmw2[j] = acc;
  }
}

// ---------------------------------------------------------------------------
// Split combined weights to transposed bf16 hi/lo:
//   Wt1 (192x128): rows 0-63 = Wa1[0:64], rows 64-191 = Wc1   -> w1h/w1l [128][192]
//   Wt2 (320x128): rows 0-127 = Wa2[0:128], rows 128-319 = Wc2 -> w2h/w2l [128][320]
// ---------------------------------------------------------------------------
__global__ __launch_bounds__(256) void convsplit_kernel(
    const float* __restrict__ Wa1, const float* __restrict__ Wc1,
    const float* __restrict__ Wa2, const float* __restrict__ Wc2,
    unsigned short* __restrict__ w1h, unsigned short* __restrict__ w1l,
    unsigned short* __restrict__ w2h, unsigned short* __restrict__ w2l)
{
  int idx = blockIdx.x * 256 + threadIdx.x;   // 65536 total
  float f;
  unsigned short* hp;
  unsigned short* lp;
  size_t off;
  if (idx < 192 * 128) {
    int t = idx >> 7, c = idx & 127;
    f = (t < 64) ? Wa1[t * 128 + c] : Wc1[(t - 64) * 128 + c];
    hp = w1h; lp = w1l; off = (size_t)c * 192 + t;
  } else {
    int i2 = idx - 192 * 128;
    int t = i2 >> 7, c = i2 & 127;
    f = (t < 128) ? Wa2[t * 128 + c] : Wc2[(t - 128) * 128 + c];
    hp = w2h; lp = w2l; off = (size_t)c * 320 + t;
  }
  unsigned u = __float_as_uint(f);
  unsigned hb = (u + 0x7fffu + ((u >> 16) & 1u)) >> 16;       // RNE bf16
  float hf = __uint_as_float(hb << 16);
  float d = f - hf;
  unsigned v = __float_as_uint(d);
  unsigned lb = (v + 0x7fffu + ((v >> 16) & 1u)) >> 16;
  hp[off] = (unsigned short)hb;
  lp[off] = (unsigned short)lb;
}

// ---------------------------------------------------------------------------
// CSR build (R2-proven)
// ---------------------------------------------------------------------------
__global__ __launch_bounds__(256) void hist_kernel(
    const int* __restrict__ dst, int* __restrict__ deg, int E)
{
  int e = blockIdx.x * 256 + threadIdx.x;
  if (e < E) atomicAdd(&deg[dst[e]], 1);
}

__global__ __launch_bounds__(256) void scan_blk_kernel(
    const int* __restrict__ in, int* __restrict__ excl, int* __restrict__ bsum, int n)
{
  __shared__ int tmp[256];
  int t = threadIdx.x;
  int i = blockIdx.x * 256 + t;
  int v = (i < n) ? in[i] : 0;
  tmp[t] = v;
  __syncthreads();
  #pragma unroll
  for (int off = 1; off < 256; off <<= 1) {
    int add = (t >= off) ? tmp[t - off] : 0;
    __syncthreads();
    tmp[t] += add;
    __syncthreads();
  }
  if (i < n) excl[i] = tmp[t] - v;
  if (t == 255 && bsum) bsum[blockIdx.x] = tmp[255];
}

__global__ __launch_bounds__(256) void finalize_rp_kernel(
    const int* __restrict__ excl, const int* __restrict__ boff,
    int* __restrict__ rp, int* __restrict__ cursor, int N, int E)
{
  int i = blockIdx.x * 256 + threadIdx.x;
  if (i < N) { int v = excl[i] + boff[i >> 8]; rp[i] = v; cursor[i] = v; }
  if (i == N) rp[N] = E;
}

__global__ __launch_bounds__(256) void scatter_kernel(
    const int* __restrict__ dst, const int* __restrict__ src,
    int* __restrict__ cursor, int* __restrict__ eidx, int* __restrict__ srcp, int E)
{
  int e = blockIdx.x * 256 + threadIdx.x;
  if (e >= E) return;
  int d = dst[e];
  int pos = atomicAdd(&cursor[d], 1);
  eidx[pos] = e;
  srcp[pos] = src[e];
}

// ---------------------------------------------------------------------------
// Fused layer-1 aggregation (R7-proven) + inline mean division.
//   meanE[n][c]  = (1/max(deg,1)) sum_e ef[e][c]     (nontemporal ef)
//   meanH1[n][c] = (1/max(deg,1)) sum_e nf[srcp][c]
// ---------------------------------------------------------------------------
__global__ __launch_bounds__(256) void csr_agg_l1_kernel(
    const float* __restrict__ ef, const float* __restrict__ nf,
    const int* __restrict__ eidx, const int* __restrict__ srcp,
    const int* __restrict__ rp, float* __restrict__ meanE,
    float* __restrict__ meanH1, int N)
{
  int node = (int)((blockIdx.x * 256u + threadIdx.x) >> 6);
  node = __builtin_amdgcn_readfirstlane(node);
  int lane = threadIdx.x & 63;
  if (node >= N) return;
  int beg = rp[node], end = rp[node + 1];

  float ea[4] = {0.f, 0.f, 0.f, 0.f}, ha[4] = {0.f, 0.f, 0.f, 0.f};
  int k = beg;
  for (; k + 7 < end; k += 8) {
    int e[8], s[8];
    #pragma unroll
    for (int j = 0; j < 8; ++j) { e[j] = eidx[k + j]; s[j] = srcp[k + j]; }
    float ev[8], hv[8];
    #pragma unroll
    for (int j = 0; j < 8; ++j) {
      ev[j] = __builtin_nontemporal_load(ef + (size_t)e[j] * 64 + lane);
      hv[j] = nf[(size_t)s[j] * 64 + lane];
    }
    #pragma unroll
    for (int j = 0; j < 8; ++j) { ea[j & 3] += ev[j]; ha[j & 3] += hv[j]; }
  }
  for (; k < end; ++k) {
    ea[0] += __builtin_nontemporal_load(ef + (size_t)eidx[k] * 64 + lane);
    ha[0] += nf[(size_t)srcp[k] * 64 + lane];
  }
  float inv = 1.0f / fmaxf((float)(end - beg), 1.0f);
  meanE [(size_t)node * 64 + lane] = ((ea[0] + ea[1]) + (ea[2] + ea[3])) * inv;
  meanH1[(size_t)node * 64 + lane] = ((ha[0] + ha[1]) + (ha[2] + ha[3])) * inv;
}

// ---------------------------------------------------------------------------
// Layer-2 aggregation D=128 (R7-proven) + inline mean division.
// ---------------------------------------------------------------------------
__global__ __launch_bounds__(256) void csr_agg128_kernel(
    const float* __restrict__ X, const int* __restrict__ srcp,
    const int* __restrict__ rp, float* __restrict__ out, int N)
{
  int node = (int)((blockIdx.x * 256u + threadIdx.x) >> 6);
  node = __builtin_amdgcn_readfirstlane(node);
  int lane = threadIdx.x & 63;
  if (node >= N) return;
  int beg = rp[node], end = rp[node + 1];

  const float2* X2 = (const float2*)X;
  float2 a[4];
  #pragma unroll
  for (int j = 0; j < 4; ++j) a[j] = make_float2(0.f, 0.f);
  int k = beg;
  for (; k + 7 < end; k += 8) {
    int s[8];
    #pragma unroll
    for (int j = 0; j < 8; ++j) s[j] = srcp[k + j];
    float2 v[8];
    #pragma unroll
    for (int j = 0; j < 8; ++j) v[j] = X2[(size_t)s[j] * 64 + lane];
    #pragma unroll
    for (int j = 0; j < 8; ++j) { a[j & 3].x += v[j].x; a[j & 3].y += v[j].y; }
  }
  for (; k < end; ++k) {
    float2 v = X2[(size_t)srcp[k] * 64 + lane];
    a[0].x += v.x; a[0].y += v.y;
  }
  float inv = 1.0f / fmaxf((float)(end - beg), 1.0f);
  ((float2*)out)[(size_t)node * 64 + lane] =
      make_float2(((a[0].x + a[1].x) + (a[2].x + a[3].x)) * inv,
                  ((a[0].y + a[1].y) + (a[2].y + a[3].y)) * inv);
}

// ---------------------------------------------------------------------------
// Fused layer GEMM: out = relu([X1||X2||X3] @ Wt + ba + (deg>0)*bmw)
// Wt transposed bf16 hi/lo [128][K]. Block = 128 rows, wave = 32 rows x 128 cols.
// ---------------------------------------------------------------------------
template<int C1, int C2, int C3>
__global__ __launch_bounds__(256, 2) void fgemm_kernel(
    const float* __restrict__ X1, const float* __restrict__ X2, const float* __restrict__ X3,
    const unsigned short* __restrict__ WtHi, const unsigned short* __restrict__ WtLo,
    const float* __restrict__ ba, const float* __restrict__ bmw,
    const int* __restrict__ deg, float* __restrict__ out, int n)
{
  constexpr int K = C1 + C2 + C3;
  const int lane = threadIdx.x & 63;
  const int w = threadIdx.x >> 6;
  const int base = blockIdx.x * 128;
  const int l15 = lane & 15;
  const int lg = lane >> 4;

  f32x4 acc[2][8] = {};

  #pragma unroll
  for (int k0 = 0; k0 < K; k0 += 32) {
    const float* sp;
    int C, off;
    if (k0 < C1)            { sp = X1; C = C1; off = k0; }
    else if (k0 < C1 + C2)  { sp = X2; C = C2; off = k0 - C1; }
    else                    { sp = X3; C = C3; off = k0 - C1 - C2; }
    const int ca = off + lg * 8;

    s16x8 ah[2], al[2];
    #pragma unroll
    for (int mi = 0; mi < 2; ++mi) {
      int row = base + w * 32 + mi * 16 + l15;
      if (row >= n) row = n - 1;
      float4 f0 = ld4(sp + (size_t)row * C + ca);
      float4 f1 = ld4(sp + (size_t)row * C + ca + 4);
      split8(f0, f1, ah[mi], al[mi]);
    }

    s16x8 bh[8], bl[8];
    const int kb = k0 + lg * 8;
    #pragma unroll
    for (int ni = 0; ni < 8; ++ni) {
      size_t woff = (size_t)(ni * 16 + l15) * K + kb;
      bh[ni] = *reinterpret_cast<const s16x8*>(WtHi + woff);
      bl[ni] = *reinterpret_cast<const s16x8*>(WtLo + woff);
    }

    #pragma unroll
    for (int mi = 0; mi < 2; ++mi)
      #pragma unroll
      for (int ni = 0; ni < 8; ++ni) {
        acc[mi][ni] = __builtin_amdgcn_mfma_f32_16x16x32_bf16(ah[mi], bh[ni], acc[mi][ni], 0, 0, 0);
        acc[mi][ni] = __builtin_amdgcn_mfma_f32_16x16x32_bf16(ah[mi], bl[ni], acc[mi][ni], 0, 0, 0);
        acc[mi][ni] = __builtin_amdgcn_mfma_f32_16x16x32_bf16(al[mi], bh[ni], acc[mi][ni], 0, 0, 0);
      }
  }

  float bav[8], bmv[8];
  #pragma unroll
  for (int ni = 0; ni < 8; ++ni) {
    bav[ni] = ba[ni * 16 + l15];
    bmv[ni] = bmw[ni * 16 + l15];
  }

  #pragma unroll
  for (int mi = 0; mi < 2; ++mi) {
    #pragma unroll
    for (int r = 0; r < 4; ++r) {
      int grow = base + w * 32 + mi * 16 + lg * 4 + r;
      if (grow >= n) continue;
      float msk = deg[grow] > 0 ? 1.0f : 0.0f;
      float* op = out + (size_t)grow * 128 + l15;
      #pragma unroll
      for (int ni = 0; ni < 8; ++ni)
        op[ni * 16] = fmaxf(acc[mi][ni][r] + bav[ni] + msk * bmv[ni], 0.0f);
    }
  }
}

// ---------------------------------------------------------------------------
// Predictor (R2-proven)
// ---------------------------------------------------------------------------
__global__ __launch_bounds__(256) void pred_node_kernel(
    const float* __restrict__ h2, const float* __restrict__ Wp,
    float* __restrict__ pt, int n)
{
  __shared__ float xs[128 * 65];
  __shared__ float wl[2560];
  const int tid = threadIdx.x;
  const int base = blockIdx.x * 64;

  for (int i = tid; i < 2560; i += 256) wl[i] = Wp[i];
  #pragma unroll
  for (int it = 0; it < 8; ++it) {
    int f = tid + it * 256;
    int r = f >> 5;
    int c = (f & 31) << 2;
    int i = base + r; if (i >= n) i = n - 1;
    float4 v = ld4(h2 + (size_t)i * 128 + c);
    xs[(c + 0) * 65 + r] = v.x; xs[(c + 1) * 65 + r] = v.y;
    xs[(c + 2) * 65 + r] = v.z; xs[(c + 3) * 65 + r] = v.w;
  }
  __syncthreads();

  int rr = tid & 63;
  int g = tid >> 6;
  int wbase[5];
  #pragma unroll
  for (int jj = 0; jj < 5; ++jj) {
    int j = g * 5 + jj;
    wbase[jj] = (j < 10) ? j : (1280 + j - 10);
  }
  float acc[5] = {};
  for (int k = 0; k < 128; ++k) {
    float xv = xs[k * 65 + rr];
    #pragma unroll
    for (int jj = 0; jj < 5; ++jj)
      acc[jj] = fmaf(xv, wl[wbase[jj] + k * 10], acc[jj]);
  }
  int ig = base + rr;
  if (ig < n) {
    #pragma unroll
    for (int jj = 0; jj < 5; ++jj)
      pt[(size_t)ig * 20 + g * 5 + jj] = acc[jj];
  }
}

__global__ __launch_bounds__(256) void pred_edge_kernel(
    const float* __restrict__ pt, const int* __restrict__ src, const int* __restrict__ dst,
    const float* __restrict__ bp, float* __restrict__ out, int E)
{
  int idx = blockIdx.x * 256 + threadIdx.x;
  if (idx >= E * 5) return;
  int e = idx / 5;
  int jj = idx - e * 5;
  int s = src[e], d = dst[e];
  const float2* p2 = (const float2*)pt;
  float2 a = p2[(size_t)s * 10 + jj];
  float2 b = p2[(size_t)d * 10 + 5 + jj];
  float2 c = ((const float2*)bp)[jj];
  ((float2*)out)[idx] = make_float2(a.x + b.x + c.x, a.y + b.y + c.y);
}

extern "C" void kernel_launch(void* const* d_in, const int* in_sizes, int n_in,
                              void* d_out, int out_size, void* d_ws, size_t ws_size,
                              hipStream_t stream) {
  const float* nfeats = (const float*)d_in[0];
  const float* efeats = (const float*)d_in[1];
  const int*   src    = (const int*)d_in[2];
  const int*   dst    = (const int*)d_in[3];
  const float* Wm1 = (const float*)d_in[4];
  const float* bm1 = (const float*)d_in[5];
  const float* Wa1 = (const float*)d_in[6];
  const float* ba1 = (const float*)d_in[7];
  const float* Wm2 = (const float*)d_in[8];
  const float* bm2 = (const float*)d_in[9];
  const float* Wa2 = (const float*)d_in[10];
  const float* ba2 = (const float*)d_in[11];
  const float* Wp  = (const float*)d_in[12];
  const float* bp  = (const float*)d_in[13];

  const int N = in_sizes[0] / 64;
  const int E = in_sizes[2];
  const int nblk = (N + 255) / 256;

  // ---- int region (R5/R6/R7-proven layout) ----
  int* ip     = (int*)d_ws;
  int* deg_i  = ip;                                  // N
  int* rp     = ip + (size_t)N;                      // N+1 (padded to +4)
  int* eidx   = ip + 2 * (size_t)N + 4;              // E
  int* scr    = ip + 2 * (size_t)N + 4 + E;          // 2N+512 CSR scratch
  int* excl   = scr;                                 // N
  int* cursor = scr + (size_t)N;                     // N
  int* bsum   = scr + 2 * (size_t)N;                 // 256
  int* boff   = bsum + 256;                          // 256

  // ---- float region ----
  size_t fbase = (4 * (size_t)N + 516 + (size_t)E + 3) & ~(size_t)3;
  float* fp     = (float*)d_ws;
  float* meanE  = fp + fbase;                     // N*64
  float* meanH1 = meanE  + (size_t)N * 64;        // N*64  (reused as pt)
  float* meanH2 = meanH1 + (size_t)N * 64;        // N*128
  float* h2     = meanH2 + (size_t)N * 128;       // N*128
  float* h1     = h2     + (size_t)N * 128;       // N*128
  float* pt     = meanH1;
  float* out    = (float*)d_out;

  // srcp + weight regions appended after floats (R7 established ws is large)
  int*   srcp = (int*)(fp + fbase + (size_t)N * 512);       // E ints
  float* wst  = fp + fbase + (size_t)N * 512 + E;           // fp32 weight scratch
  float* Wc1  = wst;                   // 128*128
  float* Wc2  = Wc1 + 128 * 128;       // 192*128
  float* bmw1 = Wc2 + 192 * 128;       // 128
  float* bmw2 = bmw1 + 128;            // 128
  unsigned short* w1h = (unsigned short*)(bmw2 + 128);  // [128][192]
  unsigned short* w1l = w1h + 192 * 128;
  unsigned short* w2h = w1l + 192 * 128;                // [128][320]
  unsigned short* w2l = w2h + 320 * 128;

  hipMemsetAsync(deg_i, 0, (size_t)N * sizeof(int), stream);

  int gridE  = (E + 255) / 256;
  int gridN  = (N + 127) / 128;
  int gridNW = ((N * 64) + 255) / 256;

  // weight prep (independent of CSR)
  wprep_kernel<<<322, 128, 0, stream>>>(Wm1, Wa1, bm1, Wm2, Wa2, bm2,
                                        Wc1, Wc2, bmw1, bmw2);
  convsplit_kernel<<<(192 * 128 + 320 * 128) / 256, 256, 0, stream>>>(
      Wa1, Wc1, Wa2, Wc2, w1h, w1l, w2h, w2l);

  // CSR build
  hist_kernel<<<gridE, 256, 0, stream>>>(dst, deg_i, E);
  scan_blk_kernel<<<nblk, 256, 0, stream>>>(deg_i, excl, bsum, N);
  scan_blk_kernel<<<1, 256, 0, stream>>>(bsum, boff, nullptr, nblk);
  finalize_rp_kernel<<<(N + 256) / 256, 256, 0, stream>>>(excl, boff, rp, cursor, N, E);
  scatter_kernel<<<gridE, 256, 0, stream>>>(dst, src, cursor, eidx, srcp, E);

  // layer 1: mean-agg then ONE fused GEMM  (h1 = relu([nf||mH1||mE]@Wt1 + ba1 + mask*bmw1))
  csr_agg_l1_kernel<<<gridNW, 256, 0, stream>>>(efeats, nfeats, eidx, srcp, rp, meanE, meanH1, N);
  fgemm_kernel<64, 64, 64><<<gridN, 256, 0, stream>>>(
      nfeats, meanH1, meanE, w1h, w1l, ba1, bmw1, deg_i, h1, N);

  // layer 2: mean-agg then ONE fused GEMM  (h2 = relu([h1||mH2||mE]@Wt2 + ba2 + mask*bmw2))
  csr_agg128_kernel<<<gridNW, 256, 0, stream>>>(h1, srcp, rp, meanH2, N);
  fgemm_kernel<128, 128, 64><<<gridN, 256, 0, stream>>>(
      h1, meanH2, meanE, w2h, w2l, ba2, bmw2, deg_i, h2, N);

  // predictor
  pred_node_kernel<<<(N + 63) / 64, 256, 0, stream>>>(h2, Wp, pt, N);
  pred_edge_kernel<<<(E * 5 + 255) / 256, 256, 0, stream>>>(pt, src, dst, bp, out, E);
}

// Round 9
// 351.309 us; speedup vs baseline: 1.3340x; 1.0439x over previous
//
#include <hip/hip_runtime.h>

typedef float  f32x4 __attribute__((ext_vector_type(4)));
typedef short  s16x8 __attribute__((ext_vector_type(8)));
typedef unsigned int u32x4 __attribute__((ext_vector_type(4)));

#define DEVINL __device__ __forceinline__

DEVINL float4 ld4(const float* p) { return *reinterpret_cast<const float4*>(p); }
DEVINL void st4(float* p, float4 v) { *reinterpret_cast<float4*>(p) = v; }
DEVINL f32x4 ld4v(const float* p) { return *reinterpret_cast<const f32x4*>(p); }
DEVINL f32x4 ld4nt(const float* p) {
  return __builtin_nontemporal_load(reinterpret_cast<const f32x4*>(p));
}

// split 8 fp32 into bf16 hi + bf16 lo fragments — pure integer ops (R5-proven).
DEVINL void split8(const float4& f0, const float4& f1, s16x8& hi, s16x8& lo) {
  unsigned hb[8], lb[8];
  const float f[8] = {f0.x, f0.y, f0.z, f0.w, f1.x, f1.y, f1.z, f1.w};
  #pragma unroll
  for (int j = 0; j < 8; ++j) {
    unsigned u = __float_as_uint(f[j]);
    unsigned h = u & 0xffff0000u;
    float l = f[j] - __uint_as_float(h);
    hb[j] = h;
    lb[j] = __float_as_uint(l) & 0xffff0000u;
  }
  u32x4 H = {(hb[0] >> 16) | hb[1], (hb[2] >> 16) | hb[3],
             (hb[4] >> 16) | hb[5], (hb[6] >> 16) | hb[7]};
  u32x4 L = {(lb[0] >> 16) | lb[1], (lb[2] >> 16) | lb[3],
             (lb[4] >> 16) | lb[5], (lb[6] >> 16) | lb[7]};
  hi = __builtin_bit_cast(s16x8, H);
  lo = __builtin_bit_cast(s16x8, L);
}

// RNE bf16 hi/lo split of one fp32 (R5-proven bit recipe)
DEVINL void split1(float f, unsigned short& h, unsigned short& l) {
  unsigned u = __float_as_uint(f);
  unsigned hb = (u + 0x7fffu + ((u >> 16) & 1u)) >> 16;
  float hf = __uint_as_float(hb << 16);
  float d = f - hf;
  unsigned v = __float_as_uint(d);
  unsigned lb = (v + 0x7fffu + ((v >> 16) & 1u)) >> 16;
  h = (unsigned short)hb;
  l = (unsigned short)lb;
}

// ---------------------------------------------------------------------------
// Weight prep, single kernel (128 threads/block, 514 blocks):
//  b in [0,128):    Wc1 row b = Wm1[b,:] @ Wa1[64:192]  -> split -> w1[:,64+b]
//  b in [128,320):  Wc2 row i = Wm2[i,:] @ Wa2[128:256] -> split -> w2[:,128+i]
//  b == 320/321:    bmw1 / bmw2 (fp32)
//  b in [322,386):  Wa1 row t=b-322 direct              -> split -> w1[:,t]
//  b in [386,514):  Wa2 row t=b-386 direct              -> split -> w2[:,t]
// ---------------------------------------------------------------------------
__global__ __launch_bounds__(128) void wprep2_kernel(
    const float* __restrict__ Wm1, const float* __restrict__ Wa1, const float* __restrict__ bm1,
    const float* __restrict__ Wm2, const float* __restrict__ Wa2, const float* __restrict__ bm2,
    float* __restrict__ bmw1, float* __restrict__ bmw2,
    unsigned short* __restrict__ w1h, unsigned short* __restrict__ w1l,
    unsigned short* __restrict__ w2h, unsigned short* __restrict__ w2l)
{
  int b = blockIdx.x, j = threadIdx.x;
  unsigned short h, l;
  if (b < 128) {
    float acc = 0.f;
    for (int k = 0; k < 128; ++k) acc = fmaf(Wm1[b * 128 + k], Wa1[(64 + k) * 128 + j], acc);
    split1(acc, h, l);
    w1h[(size_t)j * 192 + 64 + b] = h;
    w1l[(size_t)j * 192 + 64 + b] = l;
  } else if (b < 320) {
    int i = b - 128;
    float acc = 0.f;
    for (int k = 0; k < 128; ++k) acc = fmaf(Wm2[i * 128 + k], Wa2[(128 + k) * 128 + j], acc);
    split1(acc, h, l);
    w2h[(size_t)j * 320 + 128 + i] = h;
    w2l[(size_t)j * 320 + 128 + i] = l;
  } else if (b == 320) {
    float acc = 0.f;
    for (int k = 0; k < 128; ++k) acc = fmaf(bm1[k], Wa1[(64 + k) * 128 + j], acc);
    bmw1[j] = acc;
  } else if (b == 321) {
    float acc = 0.f;
    for (int k = 0; k < 128; ++k) acc = fmaf(bm2[k], Wa2[(128 + k) * 128 + j], acc);
    bmw2[j] = acc;
  } else if (b < 386) {
    int t = b - 322;
    split1(Wa1[t * 128 + j], h, l);
    w1h[(size_t)j * 192 + t] = h;
    w1l[(size_t)j * 192 + t] = l;
  } else {
    int t = b - 386;
    split1(Wa2[t * 128 + j], h, l);
    w2h[(size_t)j * 320 + t] = h;
    w2l[(size_t)j * 320 + t] = l;
  }
}

// ---------------------------------------------------------------------------
// CSR build (R2-proven); scatter writes combined int2 {e, src[e]}
// ---------------------------------------------------------------------------
__global__ __launch_bounds__(256) void hist_kernel(
    const int* __restrict__ dst, int* __restrict__ deg, int E)
{
  int e = blockIdx.x * 256 + threadIdx.x;
  if (e < E) atomicAdd(&deg[dst[e]], 1);
}

__global__ __launch_bounds__(256) void scan_blk_kernel(
    const int* __restrict__ in, int* __restrict__ excl, int* __restrict__ bsum, int n)
{
  __shared__ int tmp[256];
  int t = threadIdx.x;
  int i = blockIdx.x * 256 + t;
  int v = (i < n) ? in[i] : 0;
  tmp[t] = v;
  __syncthreads();
  #pragma unroll
  for (int off = 1; off < 256; off <<= 1) {
    int add = (t >= off) ? tmp[t - off] : 0;
    __syncthreads();
    tmp[t] += add;
    __syncthreads();
  }
  if (i < n) excl[i] = tmp[t] - v;
  if (t == 255 && bsum) bsum[blockIdx.x] = tmp[255];
}

__global__ __launch_bounds__(256) void finalize_rp_kernel(
    const int* __restrict__ excl, const int* __restrict__ boff,
    int* __restrict__ rp, int* __restrict__ cursor, int N, int E)
{
  int i = blockIdx.x * 256 + threadIdx.x;
  if (i < N) { int v = excl[i] + boff[i >> 8]; rp[i] = v; cursor[i] = v; }
  if (i == N) rp[N] = E;
}

__global__ __launch_bounds__(256) void scatter_kernel(
    const int* __restrict__ dst, const int* __restrict__ src,
    int* __restrict__ cursor, int2* __restrict__ es, int E)
{
  int e = blockIdx.x * 256 + threadIdx.x;
  if (e >= E) return;
  int d = dst[e];
  int pos = atomicAdd(&cursor[d], 1);
  es[pos] = make_int2(e, src[e]);
}

// ---------------------------------------------------------------------------
// Fused layer-1 mean aggregation: one wave per node; 4 lane-groups x float4
// (4 rows per load instruction, 16 edges per iteration), butterfly reduce.
// ---------------------------------------------------------------------------
__global__ __launch_bounds__(256) void csr_agg_l1_kernel(
    const float* __restrict__ ef, const float* __restrict__ nf,
    const int2* __restrict__ es, const int* __restrict__ rp,
    float* __restrict__ meanE, float* __restrict__ meanH1, int N)
{
  int node = (int)((blockIdx.x * 256u + threadIdx.x) >> 6);
  node = __builtin_amdgcn_readfirstlane(node);
  if (node >= N) return;
  const int lane = threadIdx.x & 63;
  const int g = lane >> 4, l16 = lane & 15;
  const int beg = rp[node], end = rp[node + 1];

  f32x4 ea = {0.f, 0.f, 0.f, 0.f}, ha = {0.f, 0.f, 0.f, 0.f};
  for (int k0 = beg; k0 < end; k0 += 16) {
    #pragma unroll
    for (int u = 0; u < 4; ++u) {
      int i = k0 + 4 * u + g;
      bool v = i < end;
      int2 p = es[v ? i : beg];
      f32x4 ev = ld4nt(ef + (size_t)p.x * 64 + l16 * 4);
      f32x4 hv = ld4v (nf + (size_t)p.y * 64 + l16 * 4);
      if (v) {
        ea += ev;
        ha += hv;
      }
    }
  }
  #pragma unroll
  for (int j = 0; j < 4; ++j) {
    ea[j] += __shfl_xor(ea[j], 16);
    ea[j] += __shfl_xor(ea[j], 32);
    ha[j] += __shfl_xor(ha[j], 16);
    ha[j] += __shfl_xor(ha[j], 32);
  }
  if (g == 0) {
    float inv = 1.0f / fmaxf((float)(end - beg), 1.0f);
    st4(meanE  + (size_t)node * 64 + l16 * 4,
        make_float4(ea[0] * inv, ea[1] * inv, ea[2] * inv, ea[3] * inv));
    st4(meanH1 + (size_t)node * 64 + l16 * 4,
        make_float4(ha[0] * inv, ha[1] * inv, ha[2] * inv, ha[3] * inv));
  }
}

// ---------------------------------------------------------------------------
// Layer-2 mean aggregation D=128: 2 lane-groups x float4 (2 rows/instr).
// ---------------------------------------------------------------------------
__global__ __launch_bounds__(256) void csr_agg128_kernel(
    const float* __restrict__ X, const int2* __restrict__ es,
    const int* __restrict__ rp, float* __restrict__ out, int N)
{
  int node = (int)((blockIdx.x * 256u + threadIdx.x) >> 6);
  node = __builtin_amdgcn_readfirstlane(node);
  if (node >= N) return;
  const int lane = threadIdx.x & 63;
  const int g = lane >> 5, l32 = lane & 31;
  const int beg = rp[node], end = rp[node + 1];

  f32x4 a = {0.f, 0.f, 0.f, 0.f};
  for (int k0 = beg; k0 < end; k0 += 8) {
    #pragma unroll
    for (int u = 0; u < 4; ++u) {
      int i = k0 + 2 * u + g;
      bool v = i < end;
      int s = es[v ? i : beg].y;
      f32x4 x = ld4v(X + (size_t)s * 128 + l32 * 4);
      if (v) a += x;
    }
  }
  #pragma unroll
  for (int j = 0; j < 4; ++j) a[j] += __shfl_xor(a[j], 32);
  if (g == 0) {
    float inv = 1.0f / fmaxf((float)(end - beg), 1.0f);
    st4(out + (size_t)node * 128 + l32 * 4,
        make_float4(a[0] * inv, a[1] * inv, a[2] * inv, a[3] * inv));
  }
}

// ---------------------------------------------------------------------------
// Layer-1 fused GEMM (R8-proven): h1 = relu([X1||X2||X3]@Wt + ba + (deg>0)*bmw)
// ---------------------------------------------------------------------------
template<int C1, int C2, int C3>
__global__ __launch_bounds__(256, 2) void fgemm_kernel(
    const float* __restrict__ X1, const float* __restrict__ X2, const float* __restrict__ X3,
    const unsigned short* __restrict__ WtHi, const unsigned short* __restrict__ WtLo,
    const float* __restrict__ ba, const float* __restrict__ bmw,
    const int* __restrict__ deg, float* __restrict__ out, int n)
{
  constexpr int K = C1 + C2 + C3;
  const int lane = threadIdx.x & 63;
  const int w = threadIdx.x >> 6;
  const int base = blockIdx.x * 128;
  const int l15 = lane & 15;
  const int lg = lane >> 4;

  f32x4 acc[2][8] = {};

  #pragma unroll
  for (int k0 = 0; k0 < K; k0 += 32) {
    const float* sp;
    int C, off;
    if (k0 < C1)            { sp = X1; C = C1; off = k0; }
    else if (k0 < C1 + C2)  { sp = X2; C = C2; off = k0 - C1; }
    else                    { sp = X3; C = C3; off = k0 - C1 - C2; }
    const int ca = off + lg * 8;

    s16x8 ah[2], al[2];
    #pragma unroll
    for (int mi = 0; mi < 2; ++mi) {
      int row = base + w * 32 + mi * 16 + l15;
      if (row >= n) row = n - 1;
      float4 f0 = ld4(sp + (size_t)row * C + ca);
      float4 f1 = ld4(sp + (size_t)row * C + ca + 4);
      split8(f0, f1, ah[mi], al[mi]);
    }

    s16x8 bh[8], bl[8];
    const int kb = k0 + lg * 8;
    #pragma unroll
    for (int ni = 0; ni < 8; ++ni) {
      size_t woff = (size_t)(ni * 16 + l15) * K + kb;
      bh[ni] = *reinterpret_cast<const s16x8*>(WtHi + woff);
      bl[ni] = *reinterpret_cast<const s16x8*>(WtLo + woff);
    }

    #pragma unroll
    for (int mi = 0; mi < 2; ++mi)
      #pragma unroll
      for (int ni = 0; ni < 8; ++ni) {
        acc[mi][ni] = __builtin_amdgcn_mfma_f32_16x16x32_bf16(ah[mi], bh[ni], acc[mi][ni], 0, 0, 0);
        acc[mi][ni] = __builtin_amdgcn_mfma_f32_16x16x32_bf16(ah[mi], bl[ni], acc[mi][ni], 0, 0, 0);
        acc[mi][ni] = __builtin_amdgcn_mfma_f32_16x16x32_bf16(al[mi], bh[ni], acc[mi][ni], 0, 0, 0);
      }
  }

  float bav[8], bmv[8];
  #pragma unroll
  for (int ni = 0; ni < 8; ++ni) {
    bav[ni] = ba[ni * 16 + l15];
    bmv[ni] = bmw[ni * 16 + l15];
  }

  #pragma unroll
  for (int mi = 0; mi < 2; ++mi) {
    #pragma unroll
    for (int r = 0; r < 4; ++r) {
      int grow = base + w * 32 + mi * 16 + lg * 4 + r;
      if (grow >= n) continue;
      float msk = deg[grow] > 0 ? 1.0f : 0.0f;
      float* op = out + (size_t)grow * 128 + l15;
      #pragma unroll
      for (int ni = 0; ni < 8; ++ni)
        op[ni * 16] = fmaxf(acc[mi][ni][r] + bav[ni] + msk * bmv[ni], 0.0f);
    }
  }
}

// ---------------------------------------------------------------------------
// Layer-2 fused GEMM + predictor projection. h2 never hits global memory:
// h2 tile -> LDS (stride 129, conflict-free) -> pt[n][20] = h2 @ Wp.
// ---------------------------------------------------------------------------
__global__ __launch_bounds__(256, 2) void fgemm2_pred_kernel(
    const float* __restrict__ X1, const float* __restrict__ X2, const float* __restrict__ X3,
    const unsigned short* __restrict__ WtHi, const unsigned short* __restrict__ WtLo,
    const float* __restrict__ ba, const float* __restrict__ bmw,
    const int* __restrict__ deg, const float* __restrict__ Wp,
    float* __restrict__ pt, int n)
{
  constexpr int C1 = 128, C2 = 128, C3 = 64;
  constexpr int K = C1 + C2 + C3;
  __shared__ float xs[128 * 129];   // h2 tile, stride 129 -> bank (r+k)%32
  __shared__ float wl[2560];        // Wp

  const int tid = threadIdx.x;
  const int lane = tid & 63;
  const int w = tid >> 6;
  const int base = blockIdx.x * 128;
  const int l15 = lane & 15;
  const int lg = lane >> 4;

  for (int i = tid; i < 2560; i += 256) wl[i] = Wp[i];

  f32x4 acc[2][8] = {};

  #pragma unroll
  for (int k0 = 0; k0 < K; k0 += 32) {
    const float* sp;
    int C, off;
    if (k0 < C1)            { sp = X1; C = C1; off = k0; }
    else if (k0 < C1 + C2)  { sp = X2; C = C2; off = k0 - C1; }
    else                    { sp = X3; C = C3; off = k0 - C1 - C2; }
    const int ca = off + lg * 8;

    s16x8 ah[2], al[2];
    #pragma unroll
    for (int mi = 0; mi < 2; ++mi) {
      int row = base + w * 32 + mi * 16 + l15;
      if (row >= n) row = n - 1;
      float4 f0 = ld4(sp + (size_t)row * C + ca);
      float4 f1 = ld4(sp + (size_t)row * C + ca + 4);
      split8(f0, f1, ah[mi], al[mi]);
    }

    s16x8 bh[8], bl[8];
    const int kb = k0 + lg * 8;
    #pragma unroll
    for (int ni = 0; ni < 8; ++ni) {
      size_t woff = (size_t)(ni * 16 + l15) * K + kb;
      bh[ni] = *reinterpret_cast<const s16x8*>(WtHi + woff);
      bl[ni] = *reinterpret_cast<const s16x8*>(WtLo + woff);
    }

    #pragma unroll
    for (int mi = 0; mi < 2; ++mi)
      #pragma unroll
      for (int ni = 0; ni < 8; ++ni) {
        acc[mi][ni] = __builtin_amdgcn_mfma_f32_16x16x32_bf16(ah[mi], bh[ni], acc[mi][ni], 0, 0, 0);
        acc[mi][ni] = __builtin_amdgcn_mfma_f32_16x16x32_bf16(ah[mi], bl[ni], acc[mi][ni], 0, 0, 0);
        acc[mi][ni] = __builtin_amdgcn_mfma_f32_16x16x32_bf16(al[mi], bh[ni], acc[mi][ni], 0, 0, 0);
      }
  }

  float bav[8], bmv[8];
  #pragma unroll
  for (int ni = 0; ni < 8; ++ni) {
    bav[ni] = ba[ni * 16 + l15];
    bmv[ni] = bmw[ni * 16 + l15];
  }

  // h2 tile -> LDS (relu'd); rows >= n left unwritten (never read back)
  #pragma unroll
  for (int mi = 0; mi < 2; ++mi) {
    #pragma unroll
    for (int r = 0; r < 4; ++r) {
      int lr = w * 32 + mi * 16 + lg * 4 + r;
      int grow = base + lr;
      if (grow >= n) continue;
      float msk = deg[grow] > 0 ? 1.0f : 0.0f;
      #pragma unroll
      for (int ni = 0; ni < 8; ++ni)
        xs[lr * 129 + ni * 16 + l15] =
            fmaxf(acc[mi][ni][r] + bav[ni] + msk * bmv[ni], 0.0f);
    }
  }
  __syncthreads();

  // predictor: pt[row][half*10 + j] = sum_k h2[row][k] * Wp[half*128 + k][j]
  const int r = tid >> 1;
  const int half = tid & 1;
  const int grow = base + r;
  if (grow < n) {
    const float* wb = wl + half * 1280;
    float a[10] = {};
    for (int k = 0; k < 128; ++k) {
      float x = xs[r * 129 + k];
      #pragma unroll
      for (int j = 0; j < 10; ++j) a[j] = fmaf(x, wb[k * 10 + j], a[j]);
    }
    float* op = pt + (size_t)grow * 20 + half * 10;
    #pragma unroll
    for (int j = 0; j < 10; ++j) op[j] = a[j];
  }
}

// ---------------------------------------------------------------------------
// Edge predictor (R6-proven float2 form)
// ---------------------------------------------------------------------------
__global__ __launch_bounds__(256) void pred_edge_kernel(
    const float* __restrict__ pt, const int* __restrict__ src, const int* __restrict__ dst,
    const float* __restrict__ bp, float* __restrict__ out, int E)
{
  int idx = blockIdx.x * 256 + threadIdx.x;
  if (idx >= E * 5) return;
  int e = idx / 5;
  int jj = idx - e * 5;
  int s = src[e], d = dst[e];
  const float2* p2 = (const float2*)pt;
  float2 a = p2[(size_t)s * 10 + jj];
  float2 b = p2[(size_t)d * 10 + 5 + jj];
  float2 c = ((const float2*)bp)[jj];
  ((float2*)out)[idx] = make_float2(a.x + b.x + c.x, a.y + b.y + c.y);
}

extern "C" void kernel_launch(void* const* d_in, const int* in_sizes, int n_in,
                              void* d_out, int out_size, void* d_ws, size_t ws_size,
                              hipStream_t stream) {
  const float* nfeats = (const float*)d_in[0];
  const float* efeats = (const float*)d_in[1];
  const int*   src    = (const int*)d_in[2];
  const int*   dst    = (const int*)d_in[3];
  const float* Wm1 = (const float*)d_in[4];
  const float* bm1 = (const float*)d_in[5];
  const float* Wa1 = (const float*)d_in[6];
  const float* ba1 = (const float*)d_in[7];
  const float* Wm2 = (const float*)d_in[8];
  const float* bm2 = (const float*)d_in[9];
  const float* Wa2 = (const float*)d_in[10];
  const float* ba2 = (const float*)d_in[11];
  const float* Wp  = (const float*)d_in[12];
  const float* bp  = (const float*)d_in[13];

  const int N = in_sizes[0] / 64;
  const int E = in_sizes[2];
  const int nblk = (N + 255) / 256;

  // ---- int region (R5..R8-proven layout; eidx slot now unused) ----
  int* ip     = (int*)d_ws;
  int* deg_i  = ip;                                  // N
  int* rp     = ip + (size_t)N;                      // N+1 (padded to +4)
  int* scr    = ip + 2 * (size_t)N + 4 + E;          // 2N+512 CSR scratch
  int* excl   = scr;                                 // N
  int* cursor = scr + (size_t)N;                     // N
  int* bsum   = scr + 2 * (size_t)N;                 // 256
  int* boff   = bsum + 256;                          // 256

  // ---- float region (R8-proven; h2 slot now unused) ----
  size_t fbase = (4 * (size_t)N + 516 + (size_t)E + 3) & ~(size_t)3;
  float* fp     = (float*)d_ws;
  float* meanE  = fp + fbase;                     // N*64
  float* meanH1 = meanE  + (size_t)N * 64;        // N*64  (reused as pt)
  float* meanH2 = meanH1 + (size_t)N * 64;        // N*128
  float* h1     = meanH2 + (size_t)N * 256;       // N*128 (same slot as R8)
  float* pt     = meanH1;
  float* out    = (float*)d_out;

  // es (int2, E entries) + weight region appended after floats
  int2*  es   = (int2*)(fp + fbase + (size_t)N * 512);
  float* wst  = fp + fbase + (size_t)N * 512 + 2 * (size_t)E;
  float* bmw1 = wst;                    // 128
  float* bmw2 = bmw1 + 128;             // 128
  unsigned short* w1h = (unsigned short*)(bmw2 + 128);  // [128][192]
  unsigned short* w1l = w1h + 192 * 128;
  unsigned short* w2h = w1l + 192 * 128;                // [128][320]
  unsigned short* w2l = w2h + 320 * 128;

  hipMemsetAsync(deg_i, 0, (size_t)N * sizeof(int), stream);

  int gridE  = (E + 255) / 256;
  int gridN  = (N + 127) / 128;
  int gridNW = ((N * 64) + 255) / 256;

  // weight prep (independent of CSR build)
  wprep2_kernel<<<514, 128, 0, stream>>>(Wm1, Wa1, bm1, Wm2, Wa2, bm2,
                                         bmw1, bmw2, w1h, w1l, w2h, w2l);

  // CSR build
  hist_kernel<<<gridE, 256, 0, stream>>>(dst, deg_i, E);
  scan_blk_kernel<<<nblk, 256, 0, stream>>>(deg_i, excl, bsum, N);
  scan_blk_kernel<<<1, 256, 0, stream>>>(bsum, boff, nullptr, nblk);
  finalize_rp_kernel<<<(N + 256) / 256, 256, 0, stream>>>(excl, boff, rp, cursor, N, E);
  scatter_kernel<<<gridE, 256, 0, stream>>>(dst, src, cursor, es, E);

  // layer 1
  csr_agg_l1_kernel<<<gridNW, 256, 0, stream>>>(efeats, nfeats, es, rp, meanE, meanH1, N);
  fgemm_kernel<64, 64, 64><<<gridN, 256, 0, stream>>>(
      nfeats, meanH1, meanE, w1h, w1l, ba1, bmw1, deg_i, h1, N);

  // layer 2 (+ fused predictor projection; h2 never materialized)
  csr_agg128_kernel<<<gridNW, 256, 0, stream>>>(h1, es, rp, meanH2, N);
  fgemm2_pred_kernel<<<gridN, 256, 0, stream>>>(
      h1, meanH2, meanE, w2h, w2l, ba2, bmw2, deg_i, Wp, pt, N);

  // edge scores
  pred_edge_kernel<<<(E * 5 + 255) / 256, 256, 0, stream>>>(pt, src, dst, bp, out, E);
}

// Round 10
// 346.243 us; speedup vs baseline: 1.3535x; 1.0146x over previous
//
#include <hip/hip_runtime.h>

typedef float  f32x4 __attribute__((ext_vector_type(4)));
typedef short  s16x8 __attribute__((ext_vector_type(8)));
typedef unsigned int u32x4 __attribute__((ext_vector_type(4)));

#define DEVINL __device__ __forceinline__

DEVINL float4 ld4(const float* p) { return *reinterpret_cast<const float4*>(p); }
DEVINL void st4(float* p, float4 v) { *reinterpret_cast<float4*>(p) = v; }
DEVINL f32x4 ld4v(const float* p) { return *reinterpret_cast<const f32x4*>(p); }
DEVINL f32x4 ld4nt(const float* p) {
  return __builtin_nontemporal_load(reinterpret_cast<const f32x4*>(p));
}

// split 8 fp32 into bf16 hi + bf16 lo fragments — pure integer ops (R5-proven).
DEVINL void split8(const float4& f0, const float4& f1, s16x8& hi, s16x8& lo) {
  unsigned hb[8], lb[8];
  const float f[8] = {f0.x, f0.y, f0.z, f0.w, f1.x, f1.y, f1.z, f1.w};
  #pragma unroll
  for (int j = 0; j < 8; ++j) {
    unsigned u = __float_as_uint(f[j]);
    unsigned h = u & 0xffff0000u;
    float l = f[j] - __uint_as_float(h);
    hb[j] = h;
    lb[j] = __float_as_uint(l) & 0xffff0000u;
  }
  u32x4 H = {(hb[0] >> 16) | hb[1], (hb[2] >> 16) | hb[3],
             (hb[4] >> 16) | hb[5], (hb[6] >> 16) | hb[7]};
  u32x4 L = {(lb[0] >> 16) | lb[1], (lb[2] >> 16) | lb[3],
             (lb[4] >> 16) | lb[5], (lb[6] >> 16) | lb[7]};
  hi = __builtin_bit_cast(s16x8, H);
  lo = __builtin_bit_cast(s16x8, L);
}

// RNE bf16 hi/lo split of one fp32 (R5-proven bit recipe)
DEVINL void split1(float f, unsigned short& h, unsigned short& l) {
  unsigned u = __float_as_uint(f);
  unsigned hb = (u + 0x7fffu + ((u >> 16) & 1u)) >> 16;
  float hf = __uint_as_float(hb << 16);
  float d = f - hf;
  unsigned v = __float_as_uint(d);
  unsigned lb = (v + 0x7fffu + ((v >> 16) & 1u)) >> 16;
  h = (unsigned short)hb;
  l = (unsigned short)lb;
}

// ---------------------------------------------------------------------------
// Weight prep (R9-proven), single kernel, 514 blocks x 128 threads
// ---------------------------------------------------------------------------
__global__ __launch_bounds__(128) void wprep2_kernel(
    const float* __restrict__ Wm1, const float* __restrict__ Wa1, const float* __restrict__ bm1,
    const float* __restrict__ Wm2, const float* __restrict__ Wa2, const float* __restrict__ bm2,
    float* __restrict__ bmw1, float* __restrict__ bmw2,
    unsigned short* __restrict__ w1h, unsigned short* __restrict__ w1l,
    unsigned short* __restrict__ w2h, unsigned short* __restrict__ w2l)
{
  int b = blockIdx.x, j = threadIdx.x;
  unsigned short h, l;
  if (b < 128) {
    float acc = 0.f;
    for (int k = 0; k < 128; ++k) acc = fmaf(Wm1[b * 128 + k], Wa1[(64 + k) * 128 + j], acc);
    split1(acc, h, l);
    w1h[(size_t)j * 192 + 64 + b] = h;
    w1l[(size_t)j * 192 + 64 + b] = l;
  } else if (b < 320) {
    int i = b - 128;
    float acc = 0.f;
    for (int k = 0; k < 128; ++k) acc = fmaf(Wm2[i * 128 + k], Wa2[(128 + k) * 128 + j], acc);
    split1(acc, h, l);
    w2h[(size_t)j * 320 + 128 + i] = h;
    w2l[(size_t)j * 320 + 128 + i] = l;
  } else if (b == 320) {
    float acc = 0.f;
    for (int k = 0; k < 128; ++k) acc = fmaf(bm1[k], Wa1[(64 + k) * 128 + j], acc);
    bmw1[j] = acc;
  } else if (b == 321) {
    float acc = 0.f;
    for (int k = 0; k < 128; ++k) acc = fmaf(bm2[k], Wa2[(128 + k) * 128 + j], acc);
    bmw2[j] = acc;
  } else if (b < 386) {
    int t = b - 322;
    split1(Wa1[t * 128 + j], h, l);
    w1h[(size_t)j * 192 + t] = h;
    w1l[(size_t)j * 192 + t] = l;
  } else {
    int t = b - 386;
    split1(Wa2[t * 128 + j], h, l);
    w2h[(size_t)j * 320 + t] = h;
    w2l[(size_t)j * 320 + t] = l;
  }
}

// ---------------------------------------------------------------------------
// CSR build; finalize now folds the block-offset scan (nblk <= 256).
// ---------------------------------------------------------------------------
__global__ __launch_bounds__(256) void hist_kernel(
    const int* __restrict__ dst, int* __restrict__ deg, int E)
{
  int e = blockIdx.x * 256 + threadIdx.x;
  if (e < E) atomicAdd(&deg[dst[e]], 1);
}

__global__ __launch_bounds__(256) void scan_blk_kernel(
    const int* __restrict__ in, int* __restrict__ excl, int* __restrict__ bsum, int n)
{
  __shared__ int tmp[256];
  int t = threadIdx.x;
  int i = blockIdx.x * 256 + t;
  int v = (i < n) ? in[i] : 0;
  tmp[t] = v;
  __syncthreads();
  #pragma unroll
  for (int off = 1; off < 256; off <<= 1) {
    int add = (t >= off) ? tmp[t - off] : 0;
    __syncthreads();
    tmp[t] += add;
    __syncthreads();
  }
  if (i < n) excl[i] = tmp[t] - v;
  if (t == 255) bsum[blockIdx.x] = tmp[255];
}

// each block redundantly scans bsum (nblk <= 256) in LDS, then finalizes rp/cursor
__global__ __launch_bounds__(256) void finalize2_kernel(
    const int* __restrict__ excl, const int* __restrict__ bsum, int nblk,
    int* __restrict__ rp, int* __restrict__ cursor, int N, int E)
{
  __shared__ int bs[256];
  int t = threadIdx.x;
  bs[t] = (t < nblk) ? bsum[t] : 0;
  __syncthreads();
  #pragma unroll
  for (int off = 1; off < 256; off <<= 1) {
    int add = (t >= off) ? bs[t - off] : 0;
    __syncthreads();
    bs[t] += add;
    __syncthreads();
  }
  int i = blockIdx.x * 256 + t;
  if (i < N) {
    int blk = i >> 8;
    int boff = blk ? bs[blk - 1] : 0;
    int v = excl[i] + boff;
    rp[i] = v;
    cursor[i] = v;
  }
  if (i == N) rp[N] = E;
}

__global__ __launch_bounds__(256) void scatter_kernel(
    const int* __restrict__ dst, const int* __restrict__ src,
    int* __restrict__ cursor, int2* __restrict__ es, int E)
{
  int e = blockIdx.x * 256 + threadIdx.x;
  if (e >= E) return;
  int d = dst[e];
  int pos = atomicAdd(&cursor[d], 1);
  es[pos] = make_int2(e, src[e]);
}

// ---------------------------------------------------------------------------
// Fused layer-1 mean aggregation: one wave per node; 4 lane-groups x float4.
// Full 16-edge blocks unconditional (MLP); tail predicated (no dummy loads).
// ---------------------------------------------------------------------------
__global__ __launch_bounds__(256) void csr_agg_l1_kernel(
    const float* __restrict__ ef, const float* __restrict__ nf,
    const int2* __restrict__ es, const int* __restrict__ rp,
    float* __restrict__ meanE, float* __restrict__ meanH1, int N)
{
  int node = (int)((blockIdx.x * 256u + threadIdx.x) >> 6);
  node = __builtin_amdgcn_readfirstlane(node);
  if (node >= N) return;
  const int lane = threadIdx.x & 63;
  const int g = lane >> 4, l16 = lane & 15;
  const int beg = rp[node], end = rp[node + 1];
  const int full_end = beg + ((end - beg) & ~15);

  f32x4 ea = {0.f, 0.f, 0.f, 0.f}, ha = {0.f, 0.f, 0.f, 0.f};
  int k0 = beg;
  for (; k0 < full_end; k0 += 16) {
    #pragma unroll
    for (int u = 0; u < 4; ++u) {
      int2 p = es[k0 + 4 * u + g];
      ea += ld4nt(ef + (size_t)p.x * 64 + l16 * 4);
      ha += ld4v (nf + (size_t)p.y * 64 + l16 * 4);
    }
  }
  // predicated tail
  #pragma unroll
  for (int u = 0; u < 4; ++u) {
    int i = k0 + 4 * u + g;
    if (i < end) {
      int2 p = es[i];
      ea += ld4nt(ef + (size_t)p.x * 64 + l16 * 4);
      ha += ld4v (nf + (size_t)p.y * 64 + l16 * 4);
    }
  }
  #pragma unroll
  for (int j = 0; j < 4; ++j) {
    ea[j] += __shfl_xor(ea[j], 16);
    ea[j] += __shfl_xor(ea[j], 32);
    ha[j] += __shfl_xor(ha[j], 16);
    ha[j] += __shfl_xor(ha[j], 32);
  }
  if (g == 0) {
    float inv = 1.0f / fmaxf((float)(end - beg), 1.0f);
    st4(meanE  + (size_t)node * 64 + l16 * 4,
        make_float4(ea[0] * inv, ea[1] * inv, ea[2] * inv, ea[3] * inv));
    st4(meanH1 + (size_t)node * 64 + l16 * 4,
        make_float4(ha[0] * inv, ha[1] * inv, ha[2] * inv, ha[3] * inv));
  }
}

// ---------------------------------------------------------------------------
// Layer-2 mean aggregation D=128: 2 lane-groups x float4; predicated tail.
// ---------------------------------------------------------------------------
__global__ __launch_bounds__(256) void csr_agg128_kernel(
    const float* __restrict__ X, const int2* __restrict__ es,
    const int* __restrict__ rp, float* __restrict__ out, int N)
{
  int node = (int)((blockIdx.x * 256u + threadIdx.x) >> 6);
  node = __builtin_amdgcn_readfirstlane(node);
  if (node >= N) return;
  const int lane = threadIdx.x & 63;
  const int g = lane >> 5, l32 = lane & 31;
  const int beg = rp[node], end = rp[node + 1];
  const int full_end = beg + ((end - beg) & ~7);

  f32x4 a = {0.f, 0.f, 0.f, 0.f};
  int k0 = beg;
  for (; k0 < full_end; k0 += 8) {
    #pragma unroll
    for (int u = 0; u < 4; ++u) {
      int s = es[k0 + 2 * u + g].y;
      a += ld4v(X + (size_t)s * 128 + l32 * 4);
    }
  }
  #pragma unroll
  for (int u = 0; u < 4; ++u) {
    int i = k0 + 2 * u + g;
    if (i < end) {
      int s = es[i].y;
      a += ld4v(X + (size_t)s * 128 + l32 * 4);
    }
  }
  #pragma unroll
  for (int j = 0; j < 4; ++j) a[j] += __shfl_xor(a[j], 32);
  if (g == 0) {
    float inv = 1.0f / fmaxf((float)(end - beg), 1.0f);
    st4(out + (size_t)node * 128 + l32 * 4,
        make_float4(a[0] * inv, a[1] * inv, a[2] * inv, a[3] * inv));
  }
}

// ---------------------------------------------------------------------------
// Layer-1 fused GEMM (R8-proven): h1 = relu([X1||X2||X3]@Wt + ba + (deg>0)*bmw)
// ---------------------------------------------------------------------------
template<int C1, int C2, int C3>
__global__ __launch_bounds__(256, 2) void fgemm_kernel(
    const float* __restrict__ X1, const float* __restrict__ X2, const float* __restrict__ X3,
    const unsigned short* __restrict__ WtHi, const unsigned short* __restrict__ WtLo,
    const float* __restrict__ ba, const float* __restrict__ bmw,
    const int* __restrict__ deg, float* __restrict__ out, int n)
{
  constexpr int K = C1 + C2 + C3;
  const int lane = threadIdx.x & 63;
  const int w = threadIdx.x >> 6;
  const int base = blockIdx.x * 128;
  const int l15 = lane & 15;
  const int lg = lane >> 4;

  f32x4 acc[2][8] = {};

  #pragma unroll
  for (int k0 = 0; k0 < K; k0 += 32) {
    const float* sp;
    int C, off;
    if (k0 < C1)            { sp = X1; C = C1; off = k0; }
    else if (k0 < C1 + C2)  { sp = X2; C = C2; off = k0 - C1; }
    else                    { sp = X3; C = C3; off = k0 - C1 - C2; }
    const int ca = off + lg * 8;

    s16x8 ah[2], al[2];
    #pragma unroll
    for (int mi = 0; mi < 2; ++mi) {
      int row = base + w * 32 + mi * 16 + l15;
      if (row >= n) row = n - 1;
      float4 f0 = ld4(sp + (size_t)row * C + ca);
      float4 f1 = ld4(sp + (size_t)row * C + ca + 4);
      split8(f0, f1, ah[mi], al[mi]);
    }

    s16x8 bh[8], bl[8];
    const int kb = k0 + lg * 8;
    #pragma unroll
    for (int ni = 0; ni < 8; ++ni) {
      size_t woff = (size_t)(ni * 16 + l15) * K + kb;
      bh[ni] = *reinterpret_cast<const s16x8*>(WtHi + woff);
      bl[ni] = *reinterpret_cast<const s16x8*>(WtLo + woff);
    }

    #pragma unroll
    for (int mi = 0; mi < 2; ++mi)
      #pragma unroll
      for (int ni = 0; ni < 8; ++ni) {
        acc[mi][ni] = __builtin_amdgcn_mfma_f32_16x16x32_bf16(ah[mi], bh[ni], acc[mi][ni], 0, 0, 0);
        acc[mi][ni] = __builtin_amdgcn_mfma_f32_16x16x32_bf16(ah[mi], bl[ni], acc[mi][ni], 0, 0, 0);
        acc[mi][ni] = __builtin_amdgcn_mfma_f32_16x16x32_bf16(al[mi], bh[ni], acc[mi][ni], 0, 0, 0);
      }
  }

  float bav[8], bmv[8];
  #pragma unroll
  for (int ni = 0; ni < 8; ++ni) {
    bav[ni] = ba[ni * 16 + l15];
    bmv[ni] = bmw[ni * 16 + l15];
  }

  #pragma unroll
  for (int mi = 0; mi < 2; ++mi) {
    #pragma unroll
    for (int r = 0; r < 4; ++r) {
      int grow = base + w * 32 + mi * 16 + lg * 4 + r;
      if (grow >= n) continue;
      float msk = deg[grow] > 0 ? 1.0f : 0.0f;
      float* op = out + (size_t)grow * 128 + l15;
      #pragma unroll
      for (int ni = 0; ni < 8; ++ni)
        op[ni * 16] = fmaxf(acc[mi][ni][r] + bav[ni] + msk * bmv[ni], 0.0f);
    }
  }
}

// ---------------------------------------------------------------------------
// Layer-2 fused GEMM + predictor projection (R9-proven); bp folded into pt.
// ---------------------------------------------------------------------------
__global__ __launch_bounds__(256, 2) void fgemm2_pred_kernel(
    const float* __restrict__ X1, const float* __restrict__ X2, const float* __restrict__ X3,
    const unsigned short* __restrict__ WtHi, const unsigned short* __restrict__ WtLo,
    const float* __restrict__ ba, const float* __restrict__ bmw,
    const int* __restrict__ deg, const float* __restrict__ Wp,
    const float* __restrict__ bp, float* __restrict__ pt, int n)
{
  constexpr int C1 = 128, C2 = 128, C3 = 64;
  constexpr int K = C1 + C2 + C3;
  __shared__ float xs[128 * 129];
  __shared__ float wl[2560];

  const int tid = threadIdx.x;
  const int lane = tid & 63;
  const int w = tid >> 6;
  const int base = blockIdx.x * 128;
  const int l15 = lane & 15;
  const int lg = lane >> 4;

  for (int i = tid; i < 2560; i += 256) wl[i] = Wp[i];

  f32x4 acc[2][8] = {};

  #pragma unroll
  for (int k0 = 0; k0 < K; k0 += 32) {
    const float* sp;
    int C, off;
    if (k0 < C1)            { sp = X1; C = C1; off = k0; }
    else if (k0 < C1 + C2)  { sp = X2; C = C2; off = k0 - C1; }
    else                    { sp = X3; C = C3; off = k0 - C1 - C2; }
    const int ca = off + lg * 8;

    s16x8 ah[2], al[2];
    #pragma unroll
    for (int mi = 0; mi < 2; ++mi) {
      int row = base + w * 32 + mi * 16 + l15;
      if (row >= n) row = n - 1;
      float4 f0 = ld4(sp + (size_t)row * C + ca);
      float4 f1 = ld4(sp + (size_t)row * C + ca + 4);
      split8(f0, f1, ah[mi], al[mi]);
    }

    s16x8 bh[8], bl[8];
    const int kb = k0 + lg * 8;
    #pragma unroll
    for (int ni = 0; ni < 8; ++ni) {
      size_t woff = (size_t)(ni * 16 + l15) * K + kb;
      bh[ni] = *reinterpret_cast<const s16x8*>(WtHi + woff);
      bl[ni] = *reinterpret_cast<const s16x8*>(WtLo + woff);
    }

    #pragma unroll
    for (int mi = 0; mi < 2; ++mi)
      #pragma unroll
      for (int ni = 0; ni < 8; ++ni) {
        acc[mi][ni] = __builtin_amdgcn_mfma_f32_16x16x32_bf16(ah[mi], bh[ni], acc[mi][ni], 0, 0, 0);
        acc[mi][ni] = __builtin_amdgcn_mfma_f32_16x16x32_bf16(ah[mi], bl[ni], acc[mi][ni], 0, 0, 0);
        acc[mi][ni] = __builtin_amdgcn_mfma_f32_16x16x32_bf16(al[mi], bh[ni], acc[mi][ni], 0, 0, 0);
      }
  }

  float bav[8], bmv[8];
  #pragma unroll
  for (int ni = 0; ni < 8; ++ni) {
    bav[ni] = ba[ni * 16 + l15];
    bmv[ni] = bmw[ni * 16 + l15];
  }

  #pragma unroll
  for (int mi = 0; mi < 2; ++mi) {
    #pragma unroll
    for (int r = 0; r < 4; ++r) {
      int lr = w * 32 + mi * 16 + lg * 4 + r;
      int grow = base + lr;
      if (grow >= n) continue;
      float msk = deg[grow] > 0 ? 1.0f : 0.0f;
      #pragma unroll
      for (int ni = 0; ni < 8; ++ni)
        xs[lr * 129 + ni * 16 + l15] =
            fmaxf(acc[mi][ni][r] + bav[ni] + msk * bmv[ni], 0.0f);
    }
  }
  __syncthreads();

  const int r = tid >> 1;
  const int half = tid & 1;
  const int grow = base + r;
  if (grow < n) {
    const float* wb = wl + half * 1280;
    float a[10] = {};
    for (int k = 0; k < 128; ++k) {
      float x = xs[r * 129 + k];
      #pragma unroll
      for (int j = 0; j < 10; ++j) a[j] = fmaf(x, wb[k * 10 + j], a[j]);
    }
    float* op = pt + (size_t)grow * 20 + half * 10;
    if (half) {
      #pragma unroll
      for (int j = 0; j < 10; ++j) op[j] = a[j] + bp[j];   // fold bp into dst half
    } else {
      #pragma unroll
      for (int j = 0; j < 10; ++j) op[j] = a[j];
    }
  }
}

// ---------------------------------------------------------------------------
// Edge predictor: out[e] = pt[src[e]][0:10] + pt[dst[e]][10:20]  (bp pre-folded)
// ---------------------------------------------------------------------------
__global__ __launch_bounds__(256) void pred_edge_kernel(
    const float* __restrict__ pt, const int* __restrict__ src, const int* __restrict__ dst,
    float* __restrict__ out, int E)
{
  int idx = blockIdx.x * 256 + threadIdx.x;
  if (idx >= E * 5) return;
  int e = idx / 5;
  int jj = idx - e * 5;
  int s = src[e], d = dst[e];
  const float2* p2 = (const float2*)pt;
  float2 a = p2[(size_t)s * 10 + jj];
  float2 b = p2[(size_t)d * 10 + 5 + jj];
  ((float2*)out)[idx] = make_float2(a.x + b.x, a.y + b.y);
}

extern "C" void kernel_launch(void* const* d_in, const int* in_sizes, int n_in,
                              void* d_out, int out_size, void* d_ws, size_t ws_size,
                              hipStream_t stream) {
  const float* nfeats = (const float*)d_in[0];
  const float* efeats = (const float*)d_in[1];
  const int*   src    = (const int*)d_in[2];
  const int*   dst    = (const int*)d_in[3];
  const float* Wm1 = (const float*)d_in[4];
  const float* bm1 = (const float*)d_in[5];
  const float* Wa1 = (const float*)d_in[6];
  const float* ba1 = (const float*)d_in[7];
  const float* Wm2 = (const float*)d_in[8];
  const float* bm2 = (const float*)d_in[9];
  const float* Wa2 = (const float*)d_in[10];
  const float* ba2 = (const float*)d_in[11];
  const float* Wp  = (const float*)d_in[12];
  const float* bp  = (const float*)d_in[13];

  const int N = in_sizes[0] / 64;
  const int E = in_sizes[2];
  const int nblk = (N + 255) / 256;

  // ---- int region (R5..R9-proven layout) ----
  int* ip     = (int*)d_ws;
  int* deg_i  = ip;                                  // N
  int* rp     = ip + (size_t)N;                      // N+1 (padded to +4)
  int* scr    = ip + 2 * (size_t)N + 4 + E;          // 2N+512 CSR scratch
  int* excl   = scr;                                 // N
  int* cursor = scr + (size_t)N;                     // N
  int* bsum   = scr + 2 * (size_t)N;                 // 256

  // ---- float region (R8/R9-proven layout) ----
  size_t fbase = (4 * (size_t)N + 516 + (size_t)E + 3) & ~(size_t)3;
  float* fp     = (float*)d_ws;
  float* meanE  = fp + fbase;                     // N*64
  float* meanH1 = meanE  + (size_t)N * 64;        // N*64  (reused as pt)
  float* meanH2 = meanH1 + (size_t)N * 64;        // N*128
  float* h1     = meanH2 + (size_t)N * 256;       // N*128
  float* pt     = meanH1;
  float* out    = (float*)d_out;

  // es (int2, E entries) + weight region appended after floats
  int2*  es   = (int2*)(fp + fbase + (size_t)N * 512);
  float* wst  = fp + fbase + (size_t)N * 512 + 2 * (size_t)E;
  float* bmw1 = wst;                    // 128
  float* bmw2 = bmw1 + 128;             // 128
  unsigned short* w1h = (unsigned short*)(bmw2 + 128);  // [128][192]
  unsigned short* w1l = w1h + 192 * 128;
  unsigned short* w2h = w1l + 192 * 128;                // [128][320]
  unsigned short* w2l = w2h + 320 * 128;

  hipMemsetAsync(deg_i, 0, (size_t)N * sizeof(int), stream);

  int gridE  = (E + 255) / 256;
  int gridN  = (N + 127) / 128;
  int gridNW = ((N * 64) + 255) / 256;

  // weight prep (independent of CSR build)
  wprep2_kernel<<<514, 128, 0, stream>>>(Wm1, Wa1, bm1, Wm2, Wa2, bm2,
                                         bmw1, bmw2, w1h, w1l, w2h, w2l);

  // CSR build (scan2+finalize merged)
  hist_kernel<<<gridE, 256, 0, stream>>>(dst, deg_i, E);
  scan_blk_kernel<<<nblk, 256, 0, stream>>>(deg_i, excl, bsum, N);
  finalize2_kernel<<<(N + 256) / 256, 256, 0, stream>>>(excl, bsum, nblk, rp, cursor, N, E);
  scatter_kernel<<<gridE, 256, 0, stream>>>(dst, src, cursor, es, E);

  // layer 1
  csr_agg_l1_kernel<<<gridNW, 256, 0, stream>>>(efeats, nfeats, es, rp, meanE, meanH1, N);
  fgemm_kernel<64, 64, 64><<<gridN, 256, 0, stream>>>(
      nfeats, meanH1, meanE, w1h, w1l, ba1, bmw1, deg_i, h1, N);

  // layer 2 (+ fused predictor projection; h2 never materialized)
  csr_agg128_kernel<<<gridNW, 256, 0, stream>>>(h1, es, rp, meanH2, N);
  fgemm2_pred_kernel<<<gridN, 256, 0, stream>>>(
      h1, meanH2, meanE, w2h, w2l, ba2, bmw2, deg_i, Wp, bp, pt, N);

  // edge scores
  pred_edge_kernel<<<(E * 5 + 255) / 256, 256, 0, stream>>>(pt, src, dst, out, E);
}

// Round 11
// 345.208 us; speedup vs baseline: 1.3576x; 1.0030x over previous
//
#include <hip/hip_runtime.h>

typedef float  f32x4 __attribute__((ext_vector_type(4)));
typedef short  s16x8 __attribute__((ext_vector_type(8)));
typedef unsigned int u32x4 __attribute__((ext_vector_type(4)));

#define DEVINL __device__ __forceinline__

DEVINL float4 ld4(const float* p) { return *reinterpret_cast<const float4*>(p); }
DEVINL f32x4 ld4v(const float* p) { return *reinterpret_cast<const f32x4*>(p); }
DEVINL u32x4 ld4u(const unsigned* p) { return *reinterpret_cast<const u32x4*>(p); }
DEVINL f32x4 ld4nt(const float* p) {
  return __builtin_nontemporal_load(reinterpret_cast<const f32x4*>(p));
}

// ---- packed bf16 pair: u32 = (hi16<<16) | lo16 ; value ≈ f(hi) + f(lo) ----
DEVINL unsigned pack1(float f) {
  unsigned u = __float_as_uint(f);
  unsigned hb = (u + 0x7fffu + ((u >> 16) & 1u)) & 0xffff0000u;   // RNE bf16 (in hi pos)
  float l = f - __uint_as_float(hb);
  unsigned v = __float_as_uint(l);
  unsigned lb = (v + 0x7fffu + ((v >> 16) & 1u)) >> 16;           // RNE bf16 of residual
  return hb | lb;
}
DEVINL float unpack1(unsigned v) {
  return __uint_as_float(v & 0xffff0000u) + __uint_as_float(v << 16);
}
DEVINL f32x4 unpack4(u32x4 v) {
  f32x4 r;
  #pragma unroll
  for (int i = 0; i < 4; ++i) r[i] = unpack1(v[i]);
  return r;
}
// 8 packed (two u32x4, k ascending) -> A-fragments hi/lo (s16x8, 2 halfwords per u32)
DEVINL void unpack_frag(u32x4 a, u32x4 b, s16x8& ah, s16x8& al) {
  u32x4 H, L;
  H[0] = (a[0] >> 16) | (a[1] & 0xffff0000u);
  H[1] = (a[2] >> 16) | (a[3] & 0xffff0000u);
  H[2] = (b[0] >> 16) | (b[1] & 0xffff0000u);
  H[3] = (b[2] >> 16) | (b[3] & 0xffff0000u);
  L[0] = (a[0] & 0xffffu) | (a[1] << 16);
  L[1] = (a[2] & 0xffffu) | (a[3] << 16);
  L[2] = (b[0] & 0xffffu) | (b[1] << 16);
  L[3] = (b[2] & 0xffffu) | (b[3] << 16);
  ah = __builtin_bit_cast(s16x8, H);
  al = __builtin_bit_cast(s16x8, L);
}

// RNE bf16 hi/lo split to separate planes (weights)
DEVINL void split1(float f, unsigned short& h, unsigned short& l) {
  unsigned u = __float_as_uint(f);
  unsigned hb = (u + 0x7fffu + ((u >> 16) & 1u)) >> 16;
  float hf = __uint_as_float(hb << 16);
  float d = f - hf;
  unsigned v = __float_as_uint(d);
  unsigned lb = (v + 0x7fffu + ((v >> 16) & 1u)) >> 16;
  h = (unsigned short)hb;
  l = (unsigned short)lb;
}

// ---------------------------------------------------------------------------
// Fused prep: blocks [0,257) = weight prep (2 sub-blocks of 128 thr each);
//             blocks [257, 257+npack) = nfeats -> packed u32;
//             remaining = degree histogram.
// ---------------------------------------------------------------------------
__global__ __launch_bounds__(256) void prep_kernel(
    const float* __restrict__ Wm1, const float* __restrict__ Wa1, const float* __restrict__ bm1,
    const float* __restrict__ Wm2, const float* __restrict__ Wa2, const float* __restrict__ bm2,
    float* __restrict__ bmw1, float* __restrict__ bmw2,
    unsigned short* __restrict__ w1h, unsigned short* __restrict__ w1l,
    unsigned short* __restrict__ w2h, unsigned short* __restrict__ w2l,
    const float* __restrict__ nf, unsigned* __restrict__ nfp, int nelem,
    const int* __restrict__ dst, int* __restrict__ deg, int E, int npack)
{
  int blk = blockIdx.x;
  if (blk < 257) {
    int b = blk * 2 + (threadIdx.x >> 7);   // 0..513
    int j = threadIdx.x & 127;
    unsigned short h, l;
    if (b < 128) {
      float acc = 0.f;
      for (int k = 0; k < 128; ++k) acc = fmaf(Wm1[b * 128 + k], Wa1[(64 + k) * 128 + j], acc);
      split1(acc, h, l);
      w1h[(size_t)j * 192 + 64 + b] = h;
      w1l[(size_t)j * 192 + 64 + b] = l;
    } else if (b < 320) {
      int i = b - 128;
      float acc = 0.f;
      for (int k = 0; k < 128; ++k) acc = fmaf(Wm2[i * 128 + k], Wa2[(128 + k) * 128 + j], acc);
      split1(acc, h, l);
      w2h[(size_t)j * 320 + 128 + i] = h;
      w2l[(size_t)j * 320 + 128 + i] = l;
    } else if (b == 320) {
      float acc = 0.f;
      for (int k = 0; k < 128; ++k) acc = fmaf(bm1[k], Wa1[(64 + k) * 128 + j], acc);
      bmw1[j] = acc;
    } else if (b == 321) {
      float acc = 0.f;
      for (int k = 0; k < 128; ++k) acc = fmaf(bm2[k], Wa2[(128 + k) * 128 + j], acc);
      bmw2[j] = acc;
    } else if (b < 386) {
      int t = b - 322;
      split1(Wa1[t * 128 + j], h, l);
      w1h[(size_t)j * 192 + t] = h;
      w1l[(size_t)j * 192 + t] = l;
    } else {
      int t = b - 386;
      split1(Wa2[t * 128 + j], h, l);
      w2h[(size_t)j * 320 + t] = h;
      w2l[(size_t)j * 320 + t] = l;
    }
  } else if (blk < 257 + npack) {
    int idx = (blk - 257) * 256 + threadIdx.x;
    if (idx < nelem) nfp[idx] = pack1(nf[idx]);
  } else {
    int e = (blk - 257 - npack) * 256 + threadIdx.x;
    if (e < E) atomicAdd(&deg[dst[e]], 1);
  }
}

// ---------------------------------------------------------------------------
// CSR build (R10-proven)
// ---------------------------------------------------------------------------
__global__ __launch_bounds__(256) void scan_blk_kernel(
    const int* __restrict__ in, int* __restrict__ excl, int* __restrict__ bsum, int n)
{
  __shared__ int tmp[256];
  int t = threadIdx.x;
  int i = blockIdx.x * 256 + t;
  int v = (i < n) ? in[i] : 0;
  tmp[t] = v;
  __syncthreads();
  #pragma unroll
  for (int off = 1; off < 256; off <<= 1) {
    int add = (t >= off) ? tmp[t - off] : 0;
    __syncthreads();
    tmp[t] += add;
    __syncthreads();
  }
  if (i < n) excl[i] = tmp[t] - v;
  if (t == 255) bsum[blockIdx.x] = tmp[255];
}

__global__ __launch_bounds__(256) void finalize2_kernel(
    const int* __restrict__ excl, const int* __restrict__ bsum, int nblk,
    int* __restrict__ rp, int* __restrict__ cursor, int N, int E)
{
  __shared__ int bs[256];
  int t = threadIdx.x;
  bs[t] = (t < nblk) ? bsum[t] : 0;
  __syncthreads();
  #pragma unroll
  for (int off = 1; off < 256; off <<= 1) {
    int add = (t >= off) ? bs[t - off] : 0;
    __syncthreads();
    bs[t] += add;
    __syncthreads();
  }
  int i = blockIdx.x * 256 + t;
  if (i < N) {
    int blk = i >> 8;
    int boff = blk ? bs[blk - 1] : 0;
    int v = excl[i] + boff;
    rp[i] = v;
    cursor[i] = v;
  }
  if (i == N) rp[N] = E;
}

__global__ __launch_bounds__(256) void scatter_kernel(
    const int* __restrict__ dst, const int* __restrict__ src,
    int* __restrict__ cursor, int2* __restrict__ es, int E)
{
  int e = blockIdx.x * 256 + threadIdx.x;
  if (e >= E) return;
  int d = dst[e];
  int pos = atomicAdd(&cursor[d], 1);
  es[pos] = make_int2(e, src[e]);
}

// ---------------------------------------------------------------------------
// Layer-1 mean aggregation (R10-proven pattern); outputs PACKED u32 planes.
// ---------------------------------------------------------------------------
__global__ __launch_bounds__(256) void csr_agg_l1_kernel(
    const float* __restrict__ ef, const float* __restrict__ nf,
    const int2* __restrict__ es, const int* __restrict__ rp,
    unsigned* __restrict__ mEp, unsigned* __restrict__ mH1p, int N)
{
  int node = (int)((blockIdx.x * 256u + threadIdx.x) >> 6);
  node = __builtin_amdgcn_readfirstlane(node);
  if (node >= N) return;
  const int lane = threadIdx.x & 63;
  const int g = lane >> 4, l16 = lane & 15;
  const int beg = rp[node], end = rp[node + 1];
  const int full_end = beg + ((end - beg) & ~15);

  f32x4 ea = {0.f, 0.f, 0.f, 0.f}, ha = {0.f, 0.f, 0.f, 0.f};
  int k0 = beg;
  for (; k0 < full_end; k0 += 16) {
    #pragma unroll
    for (int u = 0; u < 4; ++u) {
      int2 p = es[k0 + 4 * u + g];
      ea += ld4nt(ef + (size_t)p.x * 64 + l16 * 4);
      ha += ld4v (nf + (size_t)p.y * 64 + l16 * 4);
    }
  }
  #pragma unroll
  for (int u = 0; u < 4; ++u) {
    int i = k0 + 4 * u + g;
    if (i < end) {
      int2 p = es[i];
      ea += ld4nt(ef + (size_t)p.x * 64 + l16 * 4);
      ha += ld4v (nf + (size_t)p.y * 64 + l16 * 4);
    }
  }
  #pragma unroll
  for (int j = 0; j < 4; ++j) {
    ea[j] += __shfl_xor(ea[j], 16);
    ea[j] += __shfl_xor(ea[j], 32);
    ha[j] += __shfl_xor(ha[j], 16);
    ha[j] += __shfl_xor(ha[j], 32);
  }
  if (g == 0) {
    float inv = 1.0f / fmaxf((float)(end - beg), 1.0f);
    u32x4 pe, ph;
    #pragma unroll
    for (int j = 0; j < 4; ++j) {
      pe[j] = pack1(ea[j] * inv);
      ph[j] = pack1(ha[j] * inv);
    }
    *reinterpret_cast<u32x4*>(mEp  + (size_t)node * 64 + l16 * 4) = pe;
    *reinterpret_cast<u32x4*>(mH1p + (size_t)node * 64 + l16 * 4) = ph;
  }
}

// ---------------------------------------------------------------------------
// Layer-2 mean aggregation: gathers PACKED h1 (same bytes as fp32),
// 16 rows in flight, outputs packed meanH2.
// ---------------------------------------------------------------------------
__global__ __launch_bounds__(256) void csr_agg128_kernel(
    const unsigned* __restrict__ X, const int2* __restrict__ es,
    const int* __restrict__ rp, unsigned* __restrict__ out, int N)
{
  int node = (int)((blockIdx.x * 256u + threadIdx.x) >> 6);
  node = __builtin_amdgcn_readfirstlane(node);
  if (node >= N) return;
  const int lane = threadIdx.x & 63;
  const int g = lane >> 5, l32 = lane & 31;
  const int beg = rp[node], end = rp[node + 1];
  const int full_end = beg + ((end - beg) & ~15);

  f32x4 a = {0.f, 0.f, 0.f, 0.f};
  int k0 = beg;
  for (; k0 < full_end; k0 += 16) {
    u32x4 v[8];
    #pragma unroll
    for (int u = 0; u < 8; ++u) {
      int s = es[k0 + 2 * u + g].y;
      v[u] = ld4u(X + (size_t)s * 128 + l32 * 4);
    }
    #pragma unroll
    for (int u = 0; u < 8; ++u) a += unpack4(v[u]);
  }
  #pragma unroll
  for (int u = 0; u < 8; ++u) {
    int i = k0 + 2 * u + g;
    if (i < end) {
      int s = es[i].y;
      a += unpack4(ld4u(X + (size_t)s * 128 + l32 * 4));
    }
  }
  #pragma unroll
  for (int j = 0; j < 4; ++j) a[j] += __shfl_xor(a[j], 32);
  if (g == 0) {
    float inv = 1.0f / fmaxf((float)(end - beg), 1.0f);
    u32x4 pv;
    #pragma unroll
    for (int j = 0; j < 4; ++j) pv[j] = pack1(a[j] * inv);
    *reinterpret_cast<u32x4*>(out + (size_t)node * 128 + l32 * 4) = pv;
  }
}

// ---------------------------------------------------------------------------
// Layer-1 fused GEMM, ALL-PACKED A-operands: h1p = pack(relu([X1||X2||X3]@Wt + b))
// ---------------------------------------------------------------------------
template<int C1, int C2, int C3>
__global__ __launch_bounds__(256, 2) void fgemm_kernel(
    const unsigned* __restrict__ X1, const unsigned* __restrict__ X2,
    const unsigned* __restrict__ X3,
    const unsigned short* __restrict__ WtHi, const unsigned short* __restrict__ WtLo,
    const float* __restrict__ ba, const float* __restrict__ bmw,
    const int* __restrict__ deg, unsigned* __restrict__ out, int n)
{
  constexpr int K = C1 + C2 + C3;
  const int lane = threadIdx.x & 63;
  const int w = threadIdx.x >> 6;
  const int base = blockIdx.x * 128;
  const int l15 = lane & 15;
  const int lg = lane >> 4;

  f32x4 acc[2][8] = {};

  #pragma unroll
  for (int k0 = 0; k0 < K; k0 += 32) {
    const unsigned* sp;
    int C, off;
    if (k0 < C1)            { sp = X1; C = C1; off = k0; }
    else if (k0 < C1 + C2)  { sp = X2; C = C2; off = k0 - C1; }
    else                    { sp = X3; C = C3; off = k0 - C1 - C2; }
    const int ca = off + lg * 8;

    s16x8 ah[2], al[2];
    #pragma unroll
    for (int mi = 0; mi < 2; ++mi) {
      int row = base + w * 32 + mi * 16 + l15;
      if (row >= n) row = n - 1;
      u32x4 p0 = ld4u(sp + (size_t)row * C + ca);
      u32x4 p1 = ld4u(sp + (size_t)row * C + ca + 4);
      unpack_frag(p0, p1, ah[mi], al[mi]);
    }

    s16x8 bh[8], bl[8];
    const int kb = k0 + lg * 8;
    #pragma unroll
    for (int ni = 0; ni < 8; ++ni) {
      size_t woff = (size_t)(ni * 16 + l15) * K + kb;
      bh[ni] = *reinterpret_cast<const s16x8*>(WtHi + woff);
      bl[ni] = *reinterpret_cast<const s16x8*>(WtLo + woff);
    }

    #pragma unroll
    for (int mi = 0; mi < 2; ++mi)
      #pragma unroll
      for (int ni = 0; ni < 8; ++ni) {
        acc[mi][ni] = __builtin_amdgcn_mfma_f32_16x16x32_bf16(ah[mi], bh[ni], acc[mi][ni], 0, 0, 0);
        acc[mi][ni] = __builtin_amdgcn_mfma_f32_16x16x32_bf16(ah[mi], bl[ni], acc[mi][ni], 0, 0, 0);
        acc[mi][ni] = __builtin_amdgcn_mfma_f32_16x16x32_bf16(al[mi], bh[ni], acc[mi][ni], 0, 0, 0);
      }
  }

  float bav[8], bmv[8];
  #pragma unroll
  for (int ni = 0; ni < 8; ++ni) {
    bav[ni] = ba[ni * 16 + l15];
    bmv[ni] = bmw[ni * 16 + l15];
  }

  #pragma unroll
  for (int mi = 0; mi < 2; ++mi) {
    #pragma unroll
    for (int r = 0; r < 4; ++r) {
      int grow = base + w * 32 + mi * 16 + lg * 4 + r;
      if (grow >= n) continue;
      float msk = deg[grow] > 0 ? 1.0f : 0.0f;
      unsigned* op = out + (size_t)grow * 128 + l15;
      #pragma unroll
      for (int ni = 0; ni < 8; ++ni)
        op[ni * 16] = pack1(fmaxf(acc[mi][ni][r] + bav[ni] + msk * bmv[ni], 0.0f));
    }
  }
}

// ---------------------------------------------------------------------------
// Layer-2 fused GEMM + predictor projection (packed A); h2 stays in LDS.
// ---------------------------------------------------------------------------
__global__ __launch_bounds__(256, 2) void fgemm2_pred_kernel(
    const unsigned* __restrict__ X1, const unsigned* __restrict__ X2,
    const unsigned* __restrict__ X3,
    const unsigned short* __restrict__ WtHi, const unsigned short* __restrict__ WtLo,
    const float* __restrict__ ba, const float* __restrict__ bmw,
    const int* __restrict__ deg, const float* __restrict__ Wp,
    const float* __restrict__ bp, float* __restrict__ pt, int n)
{
  constexpr int C1 = 128, C2 = 128, C3 = 64;
  constexpr int K = C1 + C2 + C3;
  __shared__ float xs[128 * 129];
  __shared__ float wl[2560];

  const int tid = threadIdx.x;
  const int lane = tid & 63;
  const int w = tid >> 6;
  const int base = blockIdx.x * 128;
  const int l15 = lane & 15;
  const int lg = lane >> 4;

  for (int i = tid; i < 2560; i += 256) wl[i] = Wp[i];

  f32x4 acc[2][8] = {};

  #pragma unroll
  for (int k0 = 0; k0 < K; k0 += 32) {
    const unsigned* sp;
    int C, off;
    if (k0 < C1)            { sp = X1; C = C1; off = k0; }
    else if (k0 < C1 + C2)  { sp = X2; C = C2; off = k0 - C1; }
    else                    { sp = X3; C = C3; off = k0 - C1 - C2; }
    const int ca = off + lg * 8;

    s16x8 ah[2], al[2];
    #pragma unroll
    for (int mi = 0; mi < 2; ++mi) {
      int row = base + w * 32 + mi * 16 + l15;
      if (row >= n) row = n - 1;
      u32x4 p0 = ld4u(sp + (size_t)row * C + ca);
      u32x4 p1 = ld4u(sp + (size_t)row * C + ca + 4);
      unpack_frag(p0, p1, ah[mi], al[mi]);
    }

    s16x8 bh[8], bl[8];
    const int kb = k0 + lg * 8;
    #pragma unroll
    for (int ni = 0; ni < 8; ++ni) {
      size_t woff = (size_t)(ni * 16 + l15) * K + kb;
      bh[ni] = *reinterpret_cast<const s16x8*>(WtHi + woff);
      bl[ni] = *reinterpret_cast<const s16x8*>(WtLo + woff);
    }

    #pragma unroll
    for (int mi = 0; mi < 2; ++mi)
      #pragma unroll
      for (int ni = 0; ni < 8; ++ni) {
        acc[mi][ni] = __builtin_amdgcn_mfma_f32_16x16x32_bf16(ah[mi], bh[ni], acc[mi][ni], 0, 0, 0);
        acc[mi][ni] = __builtin_amdgcn_mfma_f32_16x16x32_bf16(ah[mi], bl[ni], acc[mi][ni], 0, 0, 0);
        acc[mi][ni] = __builtin_amdgcn_mfma_f32_16x16x32_bf16(al[mi], bh[ni], acc[mi][ni], 0, 0, 0);
      }
  }

  float bav[8], bmv[8];
  #pragma unroll
  for (int ni = 0; ni < 8; ++ni) {
    bav[ni] = ba[ni * 16 + l15];
    bmv[ni] = bmw[ni * 16 + l15];
  }

  #pragma unroll
  for (int mi = 0; mi < 2; ++mi) {
    #pragma unroll
    for (int r = 0; r < 4; ++r) {
      int lr = w * 32 + mi * 16 + lg * 4 + r;
      int grow = base + lr;
      if (grow >= n) continue;
      float msk = deg[grow] > 0 ? 1.0f : 0.0f;
      #pragma unroll
      for (int ni = 0; ni < 8; ++ni)
        xs[lr * 129 + ni * 16 + l15] =
            fmaxf(acc[mi][ni][r] + bav[ni] + msk * bmv[ni], 0.0f);
    }
  }
  __syncthreads();

  const int r = tid >> 1;
  const int half = tid & 1;
  const int grow = base + r;
  if (grow < n) {
    const float* wb = wl + half * 1280;
    float a[10] = {};
    for (int k = 0; k < 128; ++k) {
      float x = xs[r * 129 + k];
      #pragma unroll
      for (int j = 0; j < 10; ++j) a[j] = fmaf(x, wb[k * 10 + j], a[j]);
    }
    float* op = pt + (size_t)grow * 20 + half * 10;
    if (half) {
      #pragma unroll
      for (int j = 0; j < 10; ++j) op[j] = a[j] + bp[j];
    } else {
      #pragma unroll
      for (int j = 0; j < 10; ++j) op[j] = a[j];
    }
  }
}

// ---------------------------------------------------------------------------
// Edge predictor (bp pre-folded)
// ---------------------------------------------------------------------------
__global__ __launch_bounds__(256) void pred_edge_kernel(
    const float* __restrict__ pt, const int* __restrict__ src, const int* __restrict__ dst,
    float* __restrict__ out, int E)
{
  int idx = blockIdx.x * 256 + threadIdx.x;
  if (idx >= E * 5) return;
  int e = idx / 5;
  int jj = idx - e * 5;
  int s = src[e], d = dst[e];
  const float2* p2 = (const float2*)pt;
  float2 a = p2[(size_t)s * 10 + jj];
  float2 b = p2[(size_t)d * 10 + 5 + jj];
  ((float2*)out)[idx] = make_float2(a.x + b.x, a.y + b.y);
}

extern "C" void kernel_launch(void* const* d_in, const int* in_sizes, int n_in,
                              void* d_out, int out_size, void* d_ws, size_t ws_size,
                              hipStream_t stream) {
  const float* nfeats = (const float*)d_in[0];
  const float* efeats = (const float*)d_in[1];
  const int*   src    = (const int*)d_in[2];
  const int*   dst    = (const int*)d_in[3];
  const float* Wm1 = (const float*)d_in[4];
  const float* bm1 = (const float*)d_in[5];
  const float* Wa1 = (const float*)d_in[6];
  const float* ba1 = (const float*)d_in[7];
  const float* Wm2 = (const float*)d_in[8];
  const float* bm2 = (const float*)d_in[9];
  const float* Wa2 = (const float*)d_in[10];
  const float* ba2 = (const float*)d_in[11];
  const float* Wp  = (const float*)d_in[12];
  const float* bp  = (const float*)d_in[13];

  const int N = in_sizes[0] / 64;
  const int E = in_sizes[2];
  const int nblk = (N + 255) / 256;

  // ---- int region (R5..R10-proven layout) ----
  int* ip     = (int*)d_ws;
  int* deg_i  = ip;                                  // N
  int* rp     = ip + (size_t)N;                      // N+1 (padded to +4)
  int* scr    = ip + 2 * (size_t)N + 4 + E;          // 2N+512 CSR scratch
  int* excl   = scr;                                 // N
  int* cursor = scr + (size_t)N;                     // N
  int* bsum   = scr + 2 * (size_t)N;                 // 256

  // ---- float/packed region (slots reuse R10 layout; packed planes same bytes) ----
  size_t fbase = (4 * (size_t)N + 516 + (size_t)E + 3) & ~(size_t)3;
  float*    fp    = (float*)d_ws;
  unsigned* mEp   = (unsigned*)(fp + fbase);              // N*64 u32 (old meanE slot)
  float*    pt    = fp + fbase + (size_t)N * 64;          // N*20 f32 (old meanH1 slot)
  unsigned* mH1p  = (unsigned*)pt;                        // same slot; dead before pt write
  unsigned* mH2p  = (unsigned*)(fp + fbase + (size_t)N * 128);  // N*128 u32 (old meanH2 slot)
  unsigned* h1p   = (unsigned*)(fp + fbase + (size_t)N * 384);  // N*128 u32 (old h1 slot)
  float*    out   = (float*)d_out;

  // es (int2), weights, nfp appended after float slots
  int2*  es   = (int2*)(fp + fbase + (size_t)N * 512);
  float* wst  = fp + fbase + (size_t)N * 512 + 2 * (size_t)E;
  float* bmw1 = wst;                    // 128
  float* bmw2 = bmw1 + 128;             // 128
  unsigned short* w1h = (unsigned short*)(bmw2 + 128);  // [128][192]
  unsigned short* w1l = w1h + 192 * 128;
  unsigned short* w2h = w1l + 192 * 128;                // [128][320]
  unsigned short* w2l = w2h + 320 * 128;
  unsigned* nfp = (unsigned*)(w2l + 320 * 128);         // N*64 u32 packed nfeats

  hipMemsetAsync(deg_i, 0, (size_t)N * sizeof(int), stream);

  int gridE  = (E + 255) / 256;
  int gridN  = (N + 127) / 128;
  int gridNW = ((N * 64) + 255) / 256;
  int npack  = (N * 64 + 255) / 256;

  // fused prep: weight prep + nfeats pack + degree histogram
  prep_kernel<<<257 + npack + gridE, 256, 0, stream>>>(
      Wm1, Wa1, bm1, Wm2, Wa2, bm2, bmw1, bmw2, w1h, w1l, w2h, w2l,
      nfeats, nfp, N * 64, dst, deg_i, E, npack);

  // CSR build
  scan_blk_kernel<<<nblk, 256, 0, stream>>>(deg_i, excl, bsum, N);
  finalize2_kernel<<<(N + 256) / 256, 256, 0, stream>>>(excl, bsum, nblk, rp, cursor, N, E);
  scatter_kernel<<<gridE, 256, 0, stream>>>(dst, src, cursor, es, E);

  // layer 1
  csr_agg_l1_kernel<<<gridNW, 256, 0, stream>>>(efeats, nfeats, es, rp, mEp, mH1p, N);
  fgemm_kernel<64, 64, 64><<<gridN, 256, 0, stream>>>(
      nfp, mH1p, mEp, w1h, w1l, ba1, bmw1, deg_i, h1p, N);

  // layer 2 (+ fused predictor projection)
  csr_agg128_kernel<<<gridNW, 256, 0, stream>>>(h1p, es, rp, mH2p, N);
  fgemm2_pred_kernel<<<gridN, 256, 0, stream>>>(
      h1p, mH2p, mEp, w2h, w2l, ba2, bmw2, deg_i, Wp, bp, pt, N);

  // edge scores
  pred_edge_kernel<<<(E * 5 + 255) / 256, 256, 0, stream>>>(pt, src, dst, out, E);
}

// Round 12
// 315.782 us; speedup vs baseline: 1.4841x; 1.0932x over previous
//
#include <hip/hip_runtime.h>

typedef float  f32x4 __attribute__((ext_vector_type(4)));
typedef short  s16x8 __attribute__((ext_vector_type(8)));
typedef unsigned short u16;
typedef u16    u16x4 __attribute__((ext_vector_type(4)));

#define DEVINL __device__ __forceinline__

DEVINL f32x4 ld4nt(const float* p) {
  return __builtin_nontemporal_load(reinterpret_cast<const f32x4*>(p));
}

// RNE bf16 hi/lo split (R5-proven bit recipe)
DEVINL void split1(float f, u16& h, u16& l) {
  unsigned u = __float_as_uint(f);
  unsigned hb = (u + 0x7fffu + ((u >> 16) & 1u)) >> 16;
  float hf = __uint_as_float(hb << 16);
  float d = f - hf;
  unsigned v = __float_as_uint(d);
  unsigned lb = (v + 0x7fffu + ((v >> 16) & 1u)) >> 16;
  h = (u16)hb;
  l = (u16)lb;
}

DEVINL f32x4 bf4_to_f32(u16x4 v) {
  f32x4 r;
  #pragma unroll
  for (int i = 0; i < 4; ++i) r[i] = __uint_as_float(((unsigned)v[i]) << 16);
  return r;
}

// ---------------------------------------------------------------------------
// Fused prep: blocks [0,257) weight prep; [257,257+npack) nfeats->hi/lo planes;
// rest = degree histogram.
// ---------------------------------------------------------------------------
__global__ __launch_bounds__(256) void prep_kernel(
    const float* __restrict__ Wm1, const float* __restrict__ Wa1, const float* __restrict__ bm1,
    const float* __restrict__ Wm2, const float* __restrict__ Wa2, const float* __restrict__ bm2,
    float* __restrict__ bmw1, float* __restrict__ bmw2,
    u16* __restrict__ w1h, u16* __restrict__ w1l,
    u16* __restrict__ w2h, u16* __restrict__ w2l,
    const float* __restrict__ nf, u16* __restrict__ nfh, u16* __restrict__ nfl,
    int nelem, const int* __restrict__ dst, int* __restrict__ deg, int E, int npack)
{
  int blk = blockIdx.x;
  if (blk < 257) {
    int b = blk * 2 + (threadIdx.x >> 7);   // 0..513
    int j = threadIdx.x & 127;
    u16 h, l;
    if (b < 128) {
      float acc = 0.f;
      for (int k = 0; k < 128; ++k) acc = fmaf(Wm1[b * 128 + k], Wa1[(64 + k) * 128 + j], acc);
      split1(acc, h, l);
      w1h[(size_t)j * 192 + 64 + b] = h;
      w1l[(size_t)j * 192 + 64 + b] = l;
    } else if (b < 320) {
      int i = b - 128;
      float acc = 0.f;
      for (int k = 0; k < 128; ++k) acc = fmaf(Wm2[i * 128 + k], Wa2[(128 + k) * 128 + j], acc);
      split1(acc, h, l);
      w2h[(size_t)j * 320 + 128 + i] = h;
      w2l[(size_t)j * 320 + 128 + i] = l;
    } else if (b == 320) {
      float acc = 0.f;
      for (int k = 0; k < 128; ++k) acc = fmaf(bm1[k], Wa1[(64 + k) * 128 + j], acc);
      bmw1[j] = acc;
    } else if (b == 321) {
      float acc = 0.f;
      for (int k = 0; k < 128; ++k) acc = fmaf(bm2[k], Wa2[(128 + k) * 128 + j], acc);
      bmw2[j] = acc;
    } else if (b < 386) {
      int t = b - 322;
      split1(Wa1[t * 128 + j], h, l);
      w1h[(size_t)j * 192 + t] = h;
      w1l[(size_t)j * 192 + t] = l;
    } else {
      int t = b - 386;
      split1(Wa2[t * 128 + j], h, l);
      w2h[(size_t)j * 320 + t] = h;
      w2l[(size_t)j * 320 + t] = l;
    }
  } else if (blk < 257 + npack) {
    int idx = (blk - 257) * 256 + threadIdx.x;
    if (idx < nelem) {
      u16 h, l;
      split1(nf[idx], h, l);
      nfh[idx] = h;
      nfl[idx] = l;
    }
  } else {
    int e = (blk - 257 - npack) * 256 + threadIdx.x;
    if (e < E) atomicAdd(&deg[dst[e]], 1);
  }
}

// ---------------------------------------------------------------------------
// CSR build (R10-proven)
// ---------------------------------------------------------------------------
__global__ __launch_bounds__(256) void scan_blk_kernel(
    const int* __restrict__ in, int* __restrict__ excl, int* __restrict__ bsum, int n)
{
  __shared__ int tmp[256];
  int t = threadIdx.x;
  int i = blockIdx.x * 256 + t;
  int v = (i < n) ? in[i] : 0;
  tmp[t] = v;
  __syncthreads();
  #pragma unroll
  for (int off = 1; off < 256; off <<= 1) {
    int add = (t >= off) ? tmp[t - off] : 0;
    __syncthreads();
    tmp[t] += add;
    __syncthreads();
  }
  if (i < n) excl[i] = tmp[t] - v;
  if (t == 255) bsum[blockIdx.x] = tmp[255];
}

__global__ __launch_bounds__(256) void finalize2_kernel(
    const int* __restrict__ excl, const int* __restrict__ bsum, int nblk,
    int* __restrict__ rp, int* __restrict__ cursor, int N, int E)
{
  __shared__ int bs[256];
  int t = threadIdx.x;
  bs[t] = (t < nblk) ? bsum[t] : 0;
  __syncthreads();
  #pragma unroll
  for (int off = 1; off < 256; off <<= 1) {
    int add = (t >= off) ? bs[t - off] : 0;
    __syncthreads();
    bs[t] += add;
    __syncthreads();
  }
  int i = blockIdx.x * 256 + t;
  if (i < N) {
    int blk = i >> 8;
    int boff = blk ? bs[blk - 1] : 0;
    int v = excl[i] + boff;
    rp[i] = v;
    cursor[i] = v;
  }
  if (i == N) rp[N] = E;
}

__global__ __launch_bounds__(256) void scatter_kernel(
    const int* __restrict__ dst, const int* __restrict__ src,
    int* __restrict__ cursor, int2* __restrict__ es, int E)
{
  int e = blockIdx.x * 256 + threadIdx.x;
  if (e >= E) return;
  int d = dst[e];
  int pos = atomicAdd(&cursor[d], 1);
  es[pos] = make_int2(e, src[e]);
}

// ---------------------------------------------------------------------------
// Layer-1 mean aggregation: ef fp32 (HBM stream) + nf HI-PLANE only (L2 table).
// Outputs hi/lo planes for meanE and meanH1.
// ---------------------------------------------------------------------------
__global__ __launch_bounds__(256) void csr_agg_l1_kernel(
    const float* __restrict__ ef, const u16* __restrict__ nfh,
    const int2* __restrict__ es, const int* __restrict__ rp,
    u16* __restrict__ mEh, u16* __restrict__ mEl,
    u16* __restrict__ mH1h, u16* __restrict__ mH1l, int N)
{
  int node = (int)((blockIdx.x * 256u + threadIdx.x) >> 6);
  node = __builtin_amdgcn_readfirstlane(node);
  if (node >= N) return;
  const int lane = threadIdx.x & 63;
  const int g = lane >> 4, l16 = lane & 15;
  const int beg = rp[node], end = rp[node + 1];
  const int full_end = beg + ((end - beg) & ~15);

  f32x4 ea = {0.f, 0.f, 0.f, 0.f}, ha = {0.f, 0.f, 0.f, 0.f};
  int k0 = beg;
  for (; k0 < full_end; k0 += 16) {
    #pragma unroll
    for (int u = 0; u < 4; ++u) {
      int2 p = es[k0 + 4 * u + g];
      ea += ld4nt(ef + (size_t)p.x * 64 + l16 * 4);
      ha += bf4_to_f32(*reinterpret_cast<const u16x4*>(nfh + (size_t)p.y * 64 + l16 * 4));
    }
  }
  #pragma unroll
  for (int u = 0; u < 4; ++u) {
    int i = k0 + 4 * u + g;
    if (i < end) {
      int2 p = es[i];
      ea += ld4nt(ef + (size_t)p.x * 64 + l16 * 4);
      ha += bf4_to_f32(*reinterpret_cast<const u16x4*>(nfh + (size_t)p.y * 64 + l16 * 4));
    }
  }
  #pragma unroll
  for (int j = 0; j < 4; ++j) {
    ea[j] += __shfl_xor(ea[j], 16);
    ea[j] += __shfl_xor(ea[j], 32);
    ha[j] += __shfl_xor(ha[j], 16);
    ha[j] += __shfl_xor(ha[j], 32);
  }
  if (g == 0) {
    float inv = 1.0f / fmaxf((float)(end - beg), 1.0f);
    u16x4 eh, el, hh, hl;
    #pragma unroll
    for (int j = 0; j < 4; ++j) {
      u16 a, b;
      split1(ea[j] * inv, a, b); eh[j] = a; el[j] = b;
      split1(ha[j] * inv, a, b); hh[j] = a; hl[j] = b;
    }
    size_t o = (size_t)node * 64 + l16 * 4;
    *reinterpret_cast<u16x4*>(mEh  + o) = eh;
    *reinterpret_cast<u16x4*>(mEl  + o) = el;
    *reinterpret_cast<u16x4*>(mH1h + o) = hh;
    *reinterpret_cast<u16x4*>(mH1l + o) = hl;
  }
}

// ---------------------------------------------------------------------------
// Layer-2 mean aggregation: gathers h1 HI-PLANE only (256 B/row), 16 deep.
// Outputs hi/lo planes for meanH2.
// ---------------------------------------------------------------------------
__global__ __launch_bounds__(256) void csr_agg128_kernel(
    const u16* __restrict__ h1h, const int2* __restrict__ es,
    const int* __restrict__ rp, u16* __restrict__ mH2h, u16* __restrict__ mH2l, int N)
{
  int node = (int)((blockIdx.x * 256u + threadIdx.x) >> 6);
  node = __builtin_amdgcn_readfirstlane(node);
  if (node >= N) return;
  const int lane = threadIdx.x & 63;
  const int g = lane >> 5, l32 = lane & 31;
  const int beg = rp[node], end = rp[node + 1];
  const int full_end = beg + ((end - beg) & ~15);

  f32x4 a = {0.f, 0.f, 0.f, 0.f};
  int k0 = beg;
  for (; k0 < full_end; k0 += 16) {
    u16x4 v[8];
    #pragma unroll
    for (int u = 0; u < 8; ++u) {
      int s = es[k0 + 2 * u + g].y;
      v[u] = *reinterpret_cast<const u16x4*>(h1h + (size_t)s * 128 + l32 * 4);
    }
    #pragma unroll
    for (int u = 0; u < 8; ++u) a += bf4_to_f32(v[u]);
  }
  #pragma unroll
  for (int u = 0; u < 8; ++u) {
    int i = k0 + 2 * u + g;
    if (i < end) {
      int s = es[i].y;
      a += bf4_to_f32(*reinterpret_cast<const u16x4*>(h1h + (size_t)s * 128 + l32 * 4));
    }
  }
  #pragma unroll
  for (int j = 0; j < 4; ++j) a[j] += __shfl_xor(a[j], 32);
  if (g == 0) {
    float inv = 1.0f / fmaxf((float)(end - beg), 1.0f);
    u16x4 ph, pl;
    #pragma unroll
    for (int j = 0; j < 4; ++j) {
      u16 x, y;
      split1(a[j] * inv, x, y);
      ph[j] = x; pl[j] = y;
    }
    size_t o = (size_t)node * 128 + l32 * 4;
    *reinterpret_cast<u16x4*>(mH2h + o) = ph;
    *reinterpret_cast<u16x4*>(mH2l + o) = pl;
  }
}

// ---------------------------------------------------------------------------
// Layer-1 fused GEMM; A-operands are hi/lo bf16 planes (direct s16x8 loads).
// Output h1 as hi/lo planes.
// ---------------------------------------------------------------------------
template<int C1, int C2, int C3>
__global__ __launch_bounds__(256, 2) void fgemm_kernel(
    const u16* __restrict__ X1h, const u16* __restrict__ X1l,
    const u16* __restrict__ X2h, const u16* __restrict__ X2l,
    const u16* __restrict__ X3h, const u16* __restrict__ X3l,
    const u16* __restrict__ WtHi, const u16* __restrict__ WtLo,
    const float* __restrict__ ba, const float* __restrict__ bmw,
    const int* __restrict__ deg, u16* __restrict__ outH, u16* __restrict__ outL, int n)
{
  constexpr int K = C1 + C2 + C3;
  const int lane = threadIdx.x & 63;
  const int w = threadIdx.x >> 6;
  const int base = blockIdx.x * 128;
  const int l15 = lane & 15;
  const int lg = lane >> 4;

  f32x4 acc[2][8] = {};

  #pragma unroll
  for (int k0 = 0; k0 < K; k0 += 32) {
    const u16 *sph, *spl;
    int C, off;
    if (k0 < C1)            { sph = X1h; spl = X1l; C = C1; off = k0; }
    else if (k0 < C1 + C2)  { sph = X2h; spl = X2l; C = C2; off = k0 - C1; }
    else                    { sph = X3h; spl = X3l; C = C3; off = k0 - C1 - C2; }
    const int ca = off + lg * 8;

    s16x8 ah[2], al[2];
    #pragma unroll
    for (int mi = 0; mi < 2; ++mi) {
      int row = base + w * 32 + mi * 16 + l15;
      if (row >= n) row = n - 1;
      ah[mi] = *reinterpret_cast<const s16x8*>(sph + (size_t)row * C + ca);
      al[mi] = *reinterpret_cast<const s16x8*>(spl + (size_t)row * C + ca);
    }

    s16x8 bh[8], bl[8];
    const int kb = k0 + lg * 8;
    #pragma unroll
    for (int ni = 0; ni < 8; ++ni) {
      size_t woff = (size_t)(ni * 16 + l15) * K + kb;
      bh[ni] = *reinterpret_cast<const s16x8*>(WtHi + woff);
      bl[ni] = *reinterpret_cast<const s16x8*>(WtLo + woff);
    }

    #pragma unroll
    for (int mi = 0; mi < 2; ++mi)
      #pragma unroll
      for (int ni = 0; ni < 8; ++ni) {
        acc[mi][ni] = __builtin_amdgcn_mfma_f32_16x16x32_bf16(ah[mi], bh[ni], acc[mi][ni], 0, 0, 0);
        acc[mi][ni] = __builtin_amdgcn_mfma_f32_16x16x32_bf16(ah[mi], bl[ni], acc[mi][ni], 0, 0, 0);
        acc[mi][ni] = __builtin_amdgcn_mfma_f32_16x16x32_bf16(al[mi], bh[ni], acc[mi][ni], 0, 0, 0);
      }
  }

  float bav[8], bmv[8];
  #pragma unroll
  for (int ni = 0; ni < 8; ++ni) {
    bav[ni] = ba[ni * 16 + l15];
    bmv[ni] = bmw[ni * 16 + l15];
  }

  #pragma unroll
  for (int mi = 0; mi < 2; ++mi) {
    #pragma unroll
    for (int r = 0; r < 4; ++r) {
      int grow = base + w * 32 + mi * 16 + lg * 4 + r;
      if (grow >= n) continue;
      float msk = deg[grow] > 0 ? 1.0f : 0.0f;
      u16* oph = outH + (size_t)grow * 128 + l15;
      u16* opl = outL + (size_t)grow * 128 + l15;
      #pragma unroll
      for (int ni = 0; ni < 8; ++ni) {
        float v = fmaxf(acc[mi][ni][r] + bav[ni] + msk * bmv[ni], 0.0f);
        u16 h, l;
        split1(v, h, l);
        oph[ni * 16] = h;
        opl[ni * 16] = l;
      }
    }
  }
}

// ---------------------------------------------------------------------------
// Layer-2 fused GEMM + predictor projection (plane A-operands); h2 in LDS only.
// ---------------------------------------------------------------------------
__global__ __launch_bounds__(256, 2) void fgemm2_pred_kernel(
    const u16* __restrict__ X1h, const u16* __restrict__ X1l,
    const u16* __restrict__ X2h, const u16* __restrict__ X2l,
    const u16* __restrict__ X3h, const u16* __restrict__ X3l,
    const u16* __restrict__ WtHi, const u16* __restrict__ WtLo,
    const float* __restrict__ ba, const float* __restrict__ bmw,
    const int* __restrict__ deg, const float* __restrict__ Wp,
    const float* __restrict__ bp, float* __restrict__ pt, int n)
{
  constexpr int C1 = 128, C2 = 128, C3 = 64;
  constexpr int K = C1 + C2 + C3;
  __shared__ float xs[128 * 129];
  __shared__ float wl[2560];

  const int tid = threadIdx.x;
  const int lane = tid & 63;
  const int w = tid >> 6;
  const int base = blockIdx.x * 128;
  const int l15 = lane & 15;
  const int lg = lane >> 4;

  for (int i = tid; i < 2560; i += 256) wl[i] = Wp[i];

  f32x4 acc[2][8] = {};

  #pragma unroll
  for (int k0 = 0; k0 < K; k0 += 32) {
    const u16 *sph, *spl;
    int C, off;
    if (k0 < C1)            { sph = X1h; spl = X1l; C = C1; off = k0; }
    else if (k0 < C1 + C2)  { sph = X2h; spl = X2l; C = C2; off = k0 - C1; }
    else                    { sph = X3h; spl = X3l; C = C3; off = k0 - C1 - C2; }
    const int ca = off + lg * 8;

    s16x8 ah[2], al[2];
    #pragma unroll
    for (int mi = 0; mi < 2; ++mi) {
      int row = base + w * 32 + mi * 16 + l15;
      if (row >= n) row = n - 1;
      ah[mi] = *reinterpret_cast<const s16x8*>(sph + (size_t)row * C + ca);
      al[mi] = *reinterpret_cast<const s16x8*>(spl + (size_t)row * C + ca);
    }

    s16x8 bh[8], bl[8];
    const int kb = k0 + lg * 8;
    #pragma unroll
    for (int ni = 0; ni < 8; ++ni) {
      size_t woff = (size_t)(ni * 16 + l15) * K + kb;
      bh[ni] = *reinterpret_cast<const s16x8*>(WtHi + woff);
      bl[ni] = *reinterpret_cast<const s16x8*>(WtLo + woff);
    }

    #pragma unroll
    for (int mi = 0; mi < 2; ++mi)
      #pragma unroll
      for (int ni = 0; ni < 8; ++ni) {
        acc[mi][ni] = __builtin_amdgcn_mfma_f32_16x16x32_bf16(ah[mi], bh[ni], acc[mi][ni], 0, 0, 0);
        acc[mi][ni] = __builtin_amdgcn_mfma_f32_16x16x32_bf16(ah[mi], bl[ni], acc[mi][ni], 0, 0, 0);
        acc[mi][ni] = __builtin_amdgcn_mfma_f32_16x16x32_bf16(al[mi], bh[ni], acc[mi][ni], 0, 0, 0);
      }
  }

  float bav[8], bmv[8];
  #pragma unroll
  for (int ni = 0; ni < 8; ++ni) {
    bav[ni] = ba[ni * 16 + l15];
    bmv[ni] = bmw[ni * 16 + l15];
  }

  #pragma unroll
  for (int mi = 0; mi < 2; ++mi) {
    #pragma unroll
    for (int r = 0; r < 4; ++r) {
      int lr = w * 32 + mi * 16 + lg * 4 + r;
      int grow = base + lr;
      if (grow >= n) continue;
      float msk = deg[grow] > 0 ? 1.0f : 0.0f;
      #pragma unroll
      for (int ni = 0; ni < 8; ++ni)
        xs[lr * 129 + ni * 16 + l15] =
            fmaxf(acc[mi][ni][r] + bav[ni] + msk * bmv[ni], 0.0f);
    }
  }
  __syncthreads();

  const int r = tid >> 1;
  const int half = tid & 1;
  const int grow = base + r;
  if (grow < n) {
    const float* wb = wl + half * 1280;
    float a[10] = {};
    for (int k = 0; k < 128; ++k) {
      float x = xs[r * 129 + k];
      #pragma unroll
      for (int j = 0; j < 10; ++j) a[j] = fmaf(x, wb[k * 10 + j], a[j]);
    }
    float* op = pt + (size_t)grow * 20 + half * 10;
    if (half) {
      #pragma unroll
      for (int j = 0; j < 10; ++j) op[j] = a[j] + bp[j];
    } else {
      #pragma unroll
      for (int j = 0; j < 10; ++j) op[j] = a[j];
    }
  }
}

// ---------------------------------------------------------------------------
// Edge predictor (bp pre-folded)
// ---------------------------------------------------------------------------
__global__ __launch_bounds__(256) void pred_edge_kernel(
    const float* __restrict__ pt, const int* __restrict__ src, const int* __restrict__ dst,
    float* __restrict__ out, int E)
{
  int idx = blockIdx.x * 256 + threadIdx.x;
  if (idx >= E * 5) return;
  int e = idx / 5;
  int jj = idx - e * 5;
  int s = src[e], d = dst[e];
  const float2* p2 = (const float2*)pt;
  float2 a = p2[(size_t)s * 10 + jj];
  float2 b = p2[(size_t)d * 10 + 5 + jj];
  ((float2*)out)[idx] = make_float2(a.x + b.x, a.y + b.y);
}

extern "C" void kernel_launch(void* const* d_in, const int* in_sizes, int n_in,
                              void* d_out, int out_size, void* d_ws, size_t ws_size,
                              hipStream_t stream) {
  const float* nfeats = (const float*)d_in[0];
  const float* efeats = (const float*)d_in[1];
  const int*   src    = (const int*)d_in[2];
  const int*   dst    = (const int*)d_in[3];
  const float* Wm1 = (const float*)d_in[4];
  const float* bm1 = (const float*)d_in[5];
  const float* Wa1 = (const float*)d_in[6];
  const float* ba1 = (const float*)d_in[7];
  const float* Wm2 = (const float*)d_in[8];
  const float* bm2 = (const float*)d_in[9];
  const float* Wa2 = (const float*)d_in[10];
  const float* ba2 = (const float*)d_in[11];
  const float* Wp  = (const float*)d_in[12];
  const float* bp  = (const float*)d_in[13];

  const int N = in_sizes[0] / 64;
  const int E = in_sizes[2];
  const int nblk = (N + 255) / 256;

  // ---- int region (R5..R11-proven layout) ----
  int* ip     = (int*)d_ws;
  int* deg_i  = ip;                                  // N
  int* rp     = ip + (size_t)N;                      // N+1 (padded to +4)
  int* scr    = ip + 2 * (size_t)N + 4 + E;          // 2N+512 CSR scratch
  int* excl   = scr;                                 // N
  int* cursor = scr + (size_t)N;                     // N
  int* bsum   = scr + 2 * (size_t)N;                 // 256

  // ---- plane region (same slot sizes as R10/R11) ----
  size_t fbase = (4 * (size_t)N + 516 + (size_t)E + 3) & ~(size_t)3;
  float* fp   = (float*)d_ws;
  u16* mEh  = (u16*)(fp + fbase);                       // N*64 u16
  u16* mEl  = mEh + (size_t)N * 64;                     // N*64 u16  [slot 0..N*64 floats)
  float* pt = fp + fbase + (size_t)N * 64;              // N*20 f32 (overlays mH1 after death)
  u16* mH1h = (u16*)pt;                                 // N*64 u16
  u16* mH1l = mH1h + (size_t)N * 64;                    // N*64 u16  [N*64..N*128)
  u16* mH2h = (u16*)(fp + fbase + (size_t)N * 128);     // N*128 u16
  u16* mH2l = mH2h + (size_t)N * 128;                   // N*128 u16 [N*128..N*256)
  u16* h1h  = (u16*)(fp + fbase + (size_t)N * 384);     // N*128 u16
  u16* h1l  = h1h + (size_t)N * 128;                    // N*128 u16 [N*384..N*512)
  float* out = (float*)d_out;

  // es (int2), weights, nf planes appended after float slots
  int2*  es   = (int2*)(fp + fbase + (size_t)N * 512);
  float* wst  = fp + fbase + (size_t)N * 512 + 2 * (size_t)E;
  float* bmw1 = wst;                    // 128
  float* bmw2 = bmw1 + 128;             // 128
  u16* w1h = (u16*)(bmw2 + 128);        // [128][192]
  u16* w1l = w1h + 192 * 128;
  u16* w2h = w1l + 192 * 128;           // [128][320]
  u16* w2l = w2h + 320 * 128;
  u16* nfh = w2l + 320 * 128;           // N*64 u16
  u16* nfl = nfh + (size_t)N * 64;      // N*64 u16

  hipMemsetAsync(deg_i, 0, (size_t)N * sizeof(int), stream);

  int gridE  = (E + 255) / 256;
  int gridN  = (N + 127) / 128;
  int gridNW = ((N * 64) + 255) / 256;
  int npack  = (N * 64 + 255) / 256;

  // fused prep: weight prep + nfeats plane split + degree histogram
  prep_kernel<<<257 + npack + gridE, 256, 0, stream>>>(
      Wm1, Wa1, bm1, Wm2, Wa2, bm2, bmw1, bmw2, w1h, w1l, w2h, w2l,
      nfeats, nfh, nfl, N * 64, dst, deg_i, E, npack);

  // CSR build
  scan_blk_kernel<<<nblk, 256, 0, stream>>>(deg_i, excl, bsum, N);
  finalize2_kernel<<<(N + 256) / 256, 256, 0, stream>>>(excl, bsum, nblk, rp, cursor, N, E);
  scatter_kernel<<<gridE, 256, 0, stream>>>(dst, src, cursor, es, E);

  // layer 1
  csr_agg_l1_kernel<<<gridNW, 256, 0, stream>>>(
      efeats, nfh, es, rp, mEh, mEl, mH1h, mH1l, N);
  fgemm_kernel<64, 64, 64><<<gridN, 256, 0, stream>>>(
      nfh, nfl, mH1h, mH1l, mEh, mEl, w1h, w1l, ba1, bmw1, deg_i, h1h, h1l, N);

  // layer 2 (+ fused predictor projection; h2 never materialized)
  csr_agg128_kernel<<<gridNW, 256, 0, stream>>>(h1h, es, rp, mH2h, mH2l, N);
  fgemm2_pred_kernel<<<gridN, 256, 0, stream>>>(
      h1h, h1l, mH2h, mH2l, mEh, mEl, w2h, w2l, ba2, bmw2, deg_i, Wp, bp, pt, N);

  // edge scores
  pred_edge_kernel<<<(E * 5 + 255) / 256, 256, 0, stream>>>(pt, src, dst, out, E);
}